// Round 8
// baseline (392.961 us; speedup 1.0000x reference)
//
#include <hip/hip_runtime.h>
#include <stdint.h>

#define B_ 4
#define S_ 1001
#define SP 1008    // padded rows (63 * 16)
#define SPAD 1024  // padded t dimension (32 * 32)
#define EIN_ 256
#define EOUT_ 64
#define H_ 10
#define NCOL 640   // H*EOUT
#define NCOL3 1920
#define SCW 1016   // sc row stride in bf16 (1008 cols + 8 pad)

typedef short bf16x8 __attribute__((ext_vector_type(8)));
typedef short bf16x4 __attribute__((ext_vector_type(4)));
typedef float f32x4 __attribute__((ext_vector_type(4)));

__device__ __forceinline__ unsigned short f2bf(float f) {
  unsigned u = __float_as_uint(f);
  u += 0x7FFFu + ((u >> 16) & 1u);  // RTNE (inputs finite)
  return (unsigned short)(u >> 16);
}
__device__ __forceinline__ float bf2f(unsigned short h) {
  return __uint_as_float(((unsigned)h) << 16);
}

// ---- kernel 1: fp32 -> bf16 (x padded, W concat) + mask zero-padded fp32 ----
__global__ __launch_bounds__(256) void convert_kernel(
    const float* __restrict__ x, const float* __restrict__ Wq,
    const float* __restrict__ Wk, const float* __restrict__ Wv,
    const float* __restrict__ mask, unsigned short* __restrict__ xbf,
    unsigned short* __restrict__ wbf, float* __restrict__ mpad) {
  int i = blockIdx.x * 256 + threadIdx.x;
  const int N1 = B_ * SP * EIN_;   // 1,032,192
  const int N2 = NCOL3 * EIN_;     // 491,520
  const int N3 = SP * SPAD;        // 1,032,192
  if (i < N1) {
    int b = i / (SP * EIN_);
    int rem = i % (SP * EIN_);
    int row = rem / EIN_;
    int e = rem % EIN_;
    float v = (row < S_) ? x[((size_t)(b * S_ + row)) * EIN_ + e] : 0.0f;
    xbf[i] = f2bf(v);
  } else if (i < N1 + N2) {
    int j = i - N1;
    int col = j / EIN_;
    int e = j % EIN_;
    int mat = col / NCOL;
    int hcol = col % NCOL;
    const float* W = (mat == 0) ? Wq : (mat == 1) ? Wk : Wv;
    wbf[j] = f2bf(W[(size_t)hcol * EIN_ + e]);
  } else if (i < N1 + N2 + N3) {
    int j = i - N1 - N2;
    int row = j >> 10;
    int col = j & 1023;
    mpad[j] = (row < S_ && col < S_) ? mask[(size_t)row * S_ + col] : 0.0f;
  }
}

// ---------------- kernel 2: projection GEMM (MFMA bf16), 6-way N split ------
__global__ __launch_bounds__(256) void proj_kernel(
    const unsigned short* __restrict__ xbf, const unsigned short* __restrict__ wbf,
    const float* __restrict__ bq, const float* __restrict__ bk,
    const float* __restrict__ bv, unsigned short* __restrict__ qbf,
    unsigned short* __restrict__ kbf, unsigned short* __restrict__ vrow) {
  int tid = threadIdx.x;
  int wv_ = tid >> 6;
  int l = tid & 63;
  int qd = l >> 4;
  int c = l & 15;
  int bid = blockIdx.x;
  int g = bid % 6;
  int t2 = bid / 6;
  int b = t2 / 63;
  int tile = t2 % 63;
  int s0 = tile * 16;

  bf16x8 af[8];
  const unsigned short* xrowp = xbf + (size_t)(b * SP + s0 + c) * EIN_;
#pragma unroll
  for (int ks = 0; ks < 8; ++ks)
    af[ks] = *(const bf16x8*)(xrowp + ks * 32 + qd * 8);

  for (int nt = g * 20 + wv_; nt < g * 20 + 20; nt += 4) {
    int col0 = nt * 16;
    f32x4 acc = {0.f, 0.f, 0.f, 0.f};
    const unsigned short* wrow = wbf + (size_t)(col0 + c) * EIN_;
#pragma unroll
    for (int ks = 0; ks < 8; ++ks) {
      bf16x8 bfg = *(const bf16x8*)(wrow + ks * 32 + qd * 8);
      acc = __builtin_amdgcn_mfma_f32_16x16x32_bf16(af[ks], bfg, acc, 0, 0, 0);
    }
    int col = col0 + c;
    int mat = col / NCOL;
    int hcol = col % NCOL;
    int hh = hcol >> 6;
    int o = hcol & 63;
    const float* bias = (mat == 0) ? bq : (mat == 1) ? bk : bv;
    float bb = bias[hcol];
    unsigned short* dst = (mat == 0) ? qbf : (mat == 1) ? kbf : vrow;
    size_t base = ((size_t)(b * H_ + hh)) * SPAD * EOUT_ + o;
#pragma unroll
    for (int i = 0; i < 4; ++i) {
      int srow = s0 + qd * 4 + i;
      float v = (srow < S_) ? (acc[i] + bb) : 0.0f;  // zero pad rows
      dst[base + (size_t)srow * EOUT_] = f2bf(v);
    }
  }
}

// ---------------- kernel 3: v [t][o] -> vT [o][t] ----------------
// Explicitly zeroes vT for t >= 1008 so attn's k-tail MFMAs see zero B.
__global__ __launch_bounds__(256) void transpose_v(
    const unsigned short* __restrict__ vrow, unsigned short* __restrict__ vT) {
  __shared__ unsigned short tl[64 * 65];
  int bid = blockIdx.x;
  int bh = bid >> 4;
  int t0 = (bid & 15) * 64;
  int tid = threadIdx.x;
#pragma unroll
  for (int i = 0; i < 16; ++i) {
    int idx = i * 256 + tid;
    int o = idx & 63;
    int t_l = idx >> 6;
    int row = t0 + t_l;
    tl[o * 65 + t_l] =
        (row < SP) ? vrow[((size_t)bh * SPAD + row) * EOUT_ + o] : (unsigned short)0;
  }
  __syncthreads();
#pragma unroll
  for (int i = 0; i < 16; ++i) {
    int idx = i * 256 + tid;
    int t_l = idx & 63;
    int o = idx >> 6;
    vT[((size_t)bh * EOUT_ + o) * SPAD + t0 + t_l] = tl[o * 65 + t_l];
  }
}

// ---------------- kernel 4: fused attention + wsum export ----------------
// EXACT round-2 structure (best measured: 90.3 us, FETCH 28 MB), plus a final
// atomic export phase replacing the entire wsum kernel: after phase B, sc holds
// loc = exp(s)*mask (bf16) and rs[] the normalizers, so
// wsum[b,s,t] = sum_h rs_h[s]*loc_h[s,t] is exported as L2-local atomicAdds.
// Partition guarantees all 10 h-blocks of a (b,tile) share one XCD -> atomics
// RMW L2-resident lines only; HBM sees the final 16 MB once. Output buffer is
// pre-zeroed by the harness.
__global__ __launch_bounds__(256, 4) void attn_kernel(
    const unsigned short* __restrict__ qbf, const unsigned short* __restrict__ kbf,
    const unsigned short* __restrict__ vT, const float* __restrict__ mpad,
    float* __restrict__ out) {
  __shared__ unsigned short sc[16 * SCW + 8];  // +8 bf16 = 16 B zero guard
  __shared__ float rs[16];

  int tid = threadIdx.x;
  int wv_ = tid >> 6;
  int l = tid & 63;
  int qd = l >> 4;
  int c = l & 15;

  int bid0 = blockIdx.x;
  int x_ = bid0 & 7;        // XCD (hw round-robins consecutive bids)
  int s_ = bid0 >> 3;       // 0..319 slot within XCD
  int xr = x_ >> 2;         // tile half (0..1)
  int xc = x_ & 3;          // batch b
  int sub = s_ / 160;       // 5-bh sub-phase (0..1)
  int m_ = s_ % 160;
  int ti = m_ / 5;          // 0..31
  int bhi = m_ % 5;
  int tile = xr * 32 + ti;  // 0..63
  if (tile >= 63) return;   // 40 pad blocks
  int bh_ = xc * 10 + sub * 5 + bhi;  // 0..39
  int b = bh_ / 10;
  int h = bh_ % 10;
  int s0 = tile * 16;

  if (tid < 16) rs[tid] = 0.0f;

  float* concat = out;  // [B,S,640]

  size_t bh = (size_t)(b * H_ + h);
  const unsigned short* qb = qbf + bh * SPAD * EOUT_;
  const unsigned short* kb = kbf + bh * SPAD * EOUT_;
  const unsigned short* vb = vT + bh * EOUT_ * SPAD;

  // ---- phase A: scores = (Q K^T)/16, bf16 into LDS; batch-4 t-tiles ----
  bf16x8 aq0 = *(const bf16x8*)(qb + (size_t)(s0 + c) * EOUT_ + qd * 8);
  bf16x8 aq1 = *(const bf16x8*)(qb + (size_t)(s0 + c) * EOUT_ + 32 + qd * 8);
#pragma unroll
  for (int g = 0; g < 4; ++g) {
    bf16x8 k0[4], k1[4];
#pragma unroll
    for (int j = 0; j < 4; ++j) {
      int t0 = (wv_ + 4 * (g * 4 + j)) * 16;
      const unsigned short* krow = kb + (size_t)(t0 + c) * EOUT_ + qd * 8;
      k0[j] = *(const bf16x8*)krow;
      k1[j] = *(const bf16x8*)(krow + 32);
    }
#pragma unroll
    for (int j = 0; j < 4; ++j) {
      f32x4 acc = {0.f, 0.f, 0.f, 0.f};
      acc = __builtin_amdgcn_mfma_f32_16x16x32_bf16(aq0, k0[j], acc, 0, 0, 0);
      acc = __builtin_amdgcn_mfma_f32_16x16x32_bf16(aq1, k1[j], acc, 0, 0, 0);
      int t0 = (wv_ + 4 * (g * 4 + j)) * 16;
#pragma unroll
      for (int i = 0; i < 4; ++i)
        sc[(qd * 4 + i) * SCW + t0 + c] = f2bf(acc[i] * 0.0625f);
    }
  }
  // cols 1008..1015 of each row + the 16 B guard after row 15 must be finite
  if (tid < 128) sc[(tid >> 3) * SCW + 1008 + (tid & 7)] = 0;
  if (tid < 8) sc[16 * SCW + tid] = 0;
  __syncthreads();

  // ---- phase B: row-per-wave; l = exp(s)*mask, rs per row; hoisted loads ----
#pragma unroll
  for (int rr = 0; rr < 4; ++rr) {
    int r = wv_ * 4 + rr;
    int srow = s0 + r;
    if (srow < S_) {
      const float* mrow = mpad + (size_t)srow * SPAD;
      bf16x4 sv[4];
      f32x4 mv[4];
      bool tail = (l < 60);
#pragma unroll
      for (int ci = 0; ci < 3; ++ci) {
        int t0c = ci * 256 + 4 * l;
        sv[ci] = *(const bf16x4*)&sc[r * SCW + t0c];
        mv[ci] = *(const f32x4*)(mrow + t0c);
      }
      if (tail) {
        int t0c = 768 + 4 * l;
        sv[3] = *(const bf16x4*)&sc[r * SCW + t0c];
        mv[3] = *(const f32x4*)(mrow + t0c);
      }
      float nacc = 0.0f;
#pragma unroll
      for (int ci = 0; ci < 3; ++ci) {
        int t0c = ci * 256 + 4 * l;
        bf16x4 lvv;
#pragma unroll
        for (int j = 0; j < 4; ++j) {
          float e = __expf(bf2f((unsigned short)sv[ci][j]));
          float lval = e * mv[ci][j];  // mpad pad cols are 0 -> lval 0
          nacc += lval * lval;
          lvv[j] = (short)f2bf(lval);
        }
        *(bf16x4*)&sc[r * SCW + t0c] = lvv;
      }
      if (tail) {  // tail chunk: cols 768..1007
        int t0c = 768 + 4 * l;
        bf16x4 lvv;
#pragma unroll
        for (int j = 0; j < 4; ++j) {
          float e = __expf(bf2f((unsigned short)sv[3][j]));
          float lval = e * mv[3][j];
          nacc += lval * lval;
          lvv[j] = (short)f2bf(lval);
        }
        *(bf16x4*)&sc[r * SCW + t0c] = lvv;
      }
      nacc += __shfl_xor(nacc, 1);
      nacc += __shfl_xor(nacc, 2);
      nacc += __shfl_xor(nacc, 4);
      nacc += __shfl_xor(nacc, 8);
      nacc += __shfl_xor(nacc, 16);
      nacc += __shfl_xor(nacc, 32);
      if (l == 0) rs[r] = 1.0f / fmaxf(sqrtf(nacc), 1e-12f);
    }
  }
  __syncthreads();

  // ---- phase D: out = (l V) * rs[row]; batch-4 ksteps ----
  f32x4 oacc = {0.f, 0.f, 0.f, 0.f};
  const unsigned short* vrow_ = vb + (size_t)(wv_ * 16 + c) * SPAD;
#pragma unroll
  for (int g = 0; g < 8; ++g) {
    bf16x8 afr[4], bfr[4];
#pragma unroll
    for (int j = 0; j < 4; ++j) {
      int kstep = g * 4 + j;
      afr[j] = *(const bf16x8*)&sc[c * SCW + kstep * 32 + qd * 8];
      bfr[j] = *(const bf16x8*)(vrow_ + kstep * 32 + qd * 8);
    }
#pragma unroll
    for (int j = 0; j < 4; ++j)
      oacc = __builtin_amdgcn_mfma_f32_16x16x32_bf16(afr[j], bfr[j], oacc, 0, 0, 0);
  }
#pragma unroll
  for (int i = 0; i < 4; ++i) {
    int row = qd * 4 + i;
    int srow = s0 + row;
    if (srow < S_)
      concat[((size_t)(b * S_) + srow) * NCOL + h * EOUT_ + wv_ * 16 + c] =
          oacc[i] * rs[row];
  }

  // ---- export phase (replaces wsum kernel) ----
  // wsum[b, s0+row, t] += rs[row] * loc[row][t]; loc lives in sc, t < 1008.
  // 16 threads per row, lanes cover 64 B contiguous chunks (coalesced RMW).
  {
    float* wsum = out + (size_t)B_ * S_ * NCOL;
    int row = tid >> 4;  // 0..15
    int srow = s0 + row;
    if (srow < S_) {
      float rsv = rs[row];
      float* wrow_g = wsum + ((size_t)b * S_ + srow) * S_;
      const unsigned short* lrow = &sc[row * SCW];
#pragma unroll
      for (int k = 0; k < 63; ++k) {
        int t = (tid & 15) + k * 16;  // 0..1007
        if (t < S_) {                 // guard cols 1001..1007 (loc there = 0)
          float lv = bf2f(lrow[t]);
          atomicAdd(&wrow_g[t], rsv * lv);
        }
      }
    }
  }
}

extern "C" void kernel_launch(void* const* d_in, const int* in_sizes, int n_in,
                              void* d_out, int out_size, void* d_ws, size_t ws_size,
                              hipStream_t stream) {
  const float* x = (const float*)d_in[0];
  const float* mask = (const float*)d_in[1];
  const float* Wq = (const float*)d_in[2];
  const float* bq = (const float*)d_in[3];
  const float* Wk = (const float*)d_in[4];
  const float* bk = (const float*)d_in[5];
  const float* Wv = (const float*)d_in[6];
  const float* bv = (const float*)d_in[7];
  float* out = (float*)d_out;

  char* ws = (char*)d_ws;
  const size_t NEED = 28147712;
  if (ws_size < NEED) return;  // fail cleanly rather than OOB
  unsigned short* xbf  = (unsigned short*)ws;              // 2,064,384 B
  unsigned short* wbf  = (unsigned short*)(ws + 2064384);  //   983,040 B
  unsigned short* qbf  = (unsigned short*)(ws + 3047424);  // 5,242,880 B
  unsigned short* kbf  = (unsigned short*)(ws + 8290304);  // 5,242,880 B
  unsigned short* vrow = (unsigned short*)(ws + 13533184); // 5,242,880 B
  unsigned short* vT   = (unsigned short*)(ws + 18776064); // 5,242,880 B
  float*          mpad = (float*)(ws + 24018944);          // 4,128,768 B

  convert_kernel<<<9984, 256, 0, stream>>>(x, Wq, Wk, Wv, mask, xbf, wbf, mpad);
  proj_kernel<<<1512, 256, 0, stream>>>(xbf, wbf, bq, bk, bv, qbf, kbf, vrow);
  transpose_v<<<640, 256, 0, stream>>>(vrow, vT);
  attn_kernel<<<2560, 256, 0, stream>>>(qbf, kbf, vT, mpad, out);
}

// Round 9
// 305.184 us; speedup vs baseline: 1.2876x; 1.2876x over previous
//
#include <hip/hip_runtime.h>
#include <stdint.h>

#define B_ 4
#define S_ 1001
#define SP 1008    // padded rows (63 * 16)
#define SPAD 1024  // padded t dimension (32 * 32)
#define EIN_ 256
#define EOUT_ 64
#define H_ 10
#define NCOL 640   // H*EOUT
#define NCOL3 1920
#define SCW 1016   // sc row stride in bf16 (1008 cols + 8 pad)

#define C1EXP 0.090168440f  // (1/16) * log2(e): exp(s/16) = exp2(s*C1EXP)

typedef short bf16x8 __attribute__((ext_vector_type(8)));
typedef short bf16x4 __attribute__((ext_vector_type(4)));
typedef float f32x4 __attribute__((ext_vector_type(4)));

__device__ __forceinline__ unsigned short f2bf(float f) {
  unsigned u = __float_as_uint(f);
  u += 0x7FFFu + ((u >> 16) & 1u);  // RTNE (inputs finite)
  return (unsigned short)(u >> 16);
}
__device__ __forceinline__ float bf2f(unsigned short h) {
  return __uint_as_float(((unsigned)h) << 16);
}

// ---- kernel 1: fp32 -> bf16 (x padded, W concat) + mask zero-padded fp32 ----
__global__ __launch_bounds__(256) void convert_kernel(
    const float* __restrict__ x, const float* __restrict__ Wq,
    const float* __restrict__ Wk, const float* __restrict__ Wv,
    const float* __restrict__ mask, unsigned short* __restrict__ xbf,
    unsigned short* __restrict__ wbf, float* __restrict__ mpad) {
  int i = blockIdx.x * 256 + threadIdx.x;
  const int N1 = B_ * SP * EIN_;   // 1,032,192
  const int N2 = NCOL3 * EIN_;     // 491,520
  const int N3 = SP * SPAD;        // 1,032,192
  if (i < N1) {
    int b = i / (SP * EIN_);
    int rem = i % (SP * EIN_);
    int row = rem / EIN_;
    int e = rem % EIN_;
    float v = (row < S_) ? x[((size_t)(b * S_ + row)) * EIN_ + e] : 0.0f;
    xbf[i] = f2bf(v);
  } else if (i < N1 + N2) {
    int j = i - N1;
    int col = j / EIN_;
    int e = j % EIN_;
    int mat = col / NCOL;
    int hcol = col % NCOL;
    const float* W = (mat == 0) ? Wq : (mat == 1) ? Wk : Wv;
    wbf[j] = f2bf(W[(size_t)hcol * EIN_ + e]);
  } else if (i < N1 + N2 + N3) {
    int j = i - N1 - N2;
    int row = j >> 10;
    int col = j & 1023;
    mpad[j] = (row < S_ && col < S_) ? mask[(size_t)row * S_ + col] : 0.0f;
  }
}

// ---------------- kernel 2: projection GEMM (MFMA bf16), 6-way N split ------
// W-fragment loads batched (4+4 in flight). [passed R5, R7]
__global__ __launch_bounds__(256, 4) void proj_kernel(
    const unsigned short* __restrict__ xbf, const unsigned short* __restrict__ wbf,
    const float* __restrict__ bq, const float* __restrict__ bk,
    const float* __restrict__ bv, unsigned short* __restrict__ qbf,
    unsigned short* __restrict__ kbf, unsigned short* __restrict__ vrow) {
  int tid = threadIdx.x;
  int wv_ = tid >> 6;
  int l = tid & 63;
  int qd = l >> 4;
  int c = l & 15;
  int bid = blockIdx.x;
  int g = bid % 6;
  int t2 = bid / 6;
  int b = t2 / 63;
  int tile = t2 % 63;
  int s0 = tile * 16;

  bf16x8 af[8];
  const unsigned short* xrowp = xbf + (size_t)(b * SP + s0 + c) * EIN_;
#pragma unroll
  for (int ks = 0; ks < 8; ++ks)
    af[ks] = *(const bf16x8*)(xrowp + ks * 32 + qd * 8);

  for (int nt = g * 20 + wv_; nt < g * 20 + 20; nt += 4) {
    int col0 = nt * 16;
    f32x4 acc = {0.f, 0.f, 0.f, 0.f};
    const unsigned short* wrow = wbf + (size_t)(col0 + c) * EIN_;
    bf16x8 bf0[4], bf1[4];
#pragma unroll
    for (int j = 0; j < 4; ++j) bf0[j] = *(const bf16x8*)(wrow + j * 32 + qd * 8);
#pragma unroll
    for (int j = 0; j < 4; ++j) bf1[j] = *(const bf16x8*)(wrow + (4 + j) * 32 + qd * 8);
#pragma unroll
    for (int j = 0; j < 4; ++j)
      acc = __builtin_amdgcn_mfma_f32_16x16x32_bf16(af[j], bf0[j], acc, 0, 0, 0);
#pragma unroll
    for (int j = 0; j < 4; ++j)
      acc = __builtin_amdgcn_mfma_f32_16x16x32_bf16(af[4 + j], bf1[j], acc, 0, 0, 0);
    int col = col0 + c;
    int mat = col / NCOL;
    int hcol = col % NCOL;
    int hh = hcol >> 6;
    int o = hcol & 63;
    const float* bias = (mat == 0) ? bq : (mat == 1) ? bk : bv;
    float bb = bias[hcol];
    unsigned short* dst = (mat == 0) ? qbf : (mat == 1) ? kbf : vrow;
    size_t base = ((size_t)(b * H_ + hh)) * SPAD * EOUT_ + o;
#pragma unroll
    for (int i = 0; i < 4; ++i) {
      int srow = s0 + qd * 4 + i;
      float v = (srow < S_) ? (acc[i] + bb) : 0.0f;  // zero pad rows
      dst[base + (size_t)srow * EOUT_] = f2bf(v);
    }
  }
}

// ---------------- kernel 3: v [t][o] -> vT [o][t] ----------------
__global__ __launch_bounds__(256) void transpose_v(
    const unsigned short* __restrict__ vrow, unsigned short* __restrict__ vT) {
  __shared__ unsigned short tl[64 * 65];
  int bid = blockIdx.x;
  int bh = bid >> 4;
  int t0 = (bid & 15) * 64;
  int tid = threadIdx.x;
#pragma unroll
  for (int i = 0; i < 16; ++i) {
    int idx = i * 256 + tid;
    int o = idx & 63;
    int t_l = idx >> 6;
    int row = t0 + t_l;
    tl[o * 65 + t_l] =
        (row < SP) ? vrow[((size_t)bh * SPAD + row) * EOUT_ + o] : (unsigned short)0;
  }
  __syncthreads();
#pragma unroll
  for (int i = 0; i < 16; ++i) {
    int idx = i * 256 + tid;
    int t_l = idx & 63;
    int o = idx >> 6;
    vT[((size_t)bh * EOUT_ + o) * SPAD + t0 + t_l] = tl[o * 65 + t_l];
  }
}

// ---------------- kernel 4: attention — EXACT round-2 build (90.3 us) -------
__global__ __launch_bounds__(256, 4) void attn_kernel(
    const unsigned short* __restrict__ qbf, const unsigned short* __restrict__ kbf,
    const unsigned short* __restrict__ vT, const float* __restrict__ mpad,
    float* __restrict__ rsbuf, float* __restrict__ out) {
  __shared__ unsigned short sc[16 * SCW + 8];  // +8 bf16 = 16 B zero guard
  __shared__ float rs[16];

  int tid = threadIdx.x;
  int wv_ = tid >> 6;
  int l = tid & 63;
  int qd = l >> 4;
  int c = l & 15;

  int bid0 = blockIdx.x;
  int x_ = bid0 & 7;        // XCD (hw round-robins consecutive bids)
  int s_ = bid0 >> 3;       // 0..319 slot within XCD
  int xr = x_ >> 2;         // tile half (0..1)
  int xc = x_ & 3;          // bh quarter (0..3)
  int sub = s_ / 160;       // 5-bh sub-phase (0..1)
  int m_ = s_ % 160;
  int ti = m_ / 5;          // 0..31
  int bhi = m_ % 5;
  int tile = xr * 32 + ti;  // 0..63
  if (tile >= 63) return;   // 40 pad blocks
  int bh_ = xc * 10 + sub * 5 + bhi;  // 0..39
  int b = bh_ / 10;
  int h = bh_ % 10;
  int s0 = tile * 16;

  if (tid < 16) rs[tid] = 0.0f;

  float* concat = out;  // [B,S,640]

  size_t bh = (size_t)(b * H_ + h);
  const unsigned short* qb = qbf + bh * SPAD * EOUT_;
  const unsigned short* kb = kbf + bh * SPAD * EOUT_;
  const unsigned short* vb = vT + bh * EOUT_ * SPAD;

  // ---- phase A: scores = (Q K^T)/16, bf16 into LDS; batch-4 t-tiles ----
  bf16x8 aq0 = *(const bf16x8*)(qb + (size_t)(s0 + c) * EOUT_ + qd * 8);
  bf16x8 aq1 = *(const bf16x8*)(qb + (size_t)(s0 + c) * EOUT_ + 32 + qd * 8);
#pragma unroll
  for (int g = 0; g < 4; ++g) {
    bf16x8 k0[4], k1[4];
#pragma unroll
    for (int j = 0; j < 4; ++j) {
      int t0 = (wv_ + 4 * (g * 4 + j)) * 16;
      const unsigned short* krow = kb + (size_t)(t0 + c) * EOUT_ + qd * 8;
      k0[j] = *(const bf16x8*)krow;
      k1[j] = *(const bf16x8*)(krow + 32);
    }
#pragma unroll
    for (int j = 0; j < 4; ++j) {
      f32x4 acc = {0.f, 0.f, 0.f, 0.f};
      acc = __builtin_amdgcn_mfma_f32_16x16x32_bf16(aq0, k0[j], acc, 0, 0, 0);
      acc = __builtin_amdgcn_mfma_f32_16x16x32_bf16(aq1, k1[j], acc, 0, 0, 0);
      int t0 = (wv_ + 4 * (g * 4 + j)) * 16;
#pragma unroll
      for (int i = 0; i < 4; ++i)
        sc[(qd * 4 + i) * SCW + t0 + c] = f2bf(acc[i] * 0.0625f);
    }
  }
  // cols 1008..1015 of each row + the 16 B guard after row 15 must be finite
  if (tid < 128) sc[(tid >> 3) * SCW + 1008 + (tid & 7)] = 0;
  if (tid < 8) sc[16 * SCW + tid] = 0;
  __syncthreads();

  // ---- phase B: row-per-wave; l = exp(s)*mask, rs per row; hoisted loads ----
#pragma unroll
  for (int rr = 0; rr < 4; ++rr) {
    int r = wv_ * 4 + rr;
    int srow = s0 + r;
    if (srow < S_) {
      const float* mrow = mpad + (size_t)srow * SPAD;
      bf16x4 sv[4];
      f32x4 mv[4];
      bool tail = (l < 60);
#pragma unroll
      for (int ci = 0; ci < 3; ++ci) {
        int t0c = ci * 256 + 4 * l;
        sv[ci] = *(const bf16x4*)&sc[r * SCW + t0c];
        mv[ci] = *(const f32x4*)(mrow + t0c);
      }
      if (tail) {
        int t0c = 768 + 4 * l;
        sv[3] = *(const bf16x4*)&sc[r * SCW + t0c];
        mv[3] = *(const f32x4*)(mrow + t0c);
      }
      float nacc = 0.0f;
#pragma unroll
      for (int ci = 0; ci < 3; ++ci) {
        int t0c = ci * 256 + 4 * l;
        bf16x4 lvv;
#pragma unroll
        for (int j = 0; j < 4; ++j) {
          float e = __expf(bf2f((unsigned short)sv[ci][j]));
          float lval = e * mv[ci][j];  // mpad pad cols are 0 -> lval 0
          nacc += lval * lval;
          lvv[j] = (short)f2bf(lval);
        }
        *(bf16x4*)&sc[r * SCW + t0c] = lvv;
      }
      if (tail) {  // tail chunk: cols 768..1007
        int t0c = 768 + 4 * l;
        bf16x4 lvv;
#pragma unroll
        for (int j = 0; j < 4; ++j) {
          float e = __expf(bf2f((unsigned short)sv[3][j]));
          float lval = e * mv[3][j];
          nacc += lval * lval;
          lvv[j] = (short)f2bf(lval);
        }
        *(bf16x4*)&sc[r * SCW + t0c] = lvv;
      }
      nacc += __shfl_xor(nacc, 1);
      nacc += __shfl_xor(nacc, 2);
      nacc += __shfl_xor(nacc, 4);
      nacc += __shfl_xor(nacc, 8);
      nacc += __shfl_xor(nacc, 16);
      nacc += __shfl_xor(nacc, 32);
      if (l == 0) rs[r] = 1.0f / fmaxf(sqrtf(nacc), 1e-12f);
    }
  }
  __syncthreads();

  if (tid < 16) rsbuf[((size_t)bh * 63 + tile) * 16 + tid] = rs[tid];

  // ---- phase D: out = (l V) * rs[row]; batch-4 ksteps ----
  f32x4 oacc = {0.f, 0.f, 0.f, 0.f};
  const unsigned short* vrow_ = vb + (size_t)(wv_ * 16 + c) * SPAD;
#pragma unroll
  for (int g = 0; g < 8; ++g) {
    bf16x8 afr[4], bfr[4];
#pragma unroll
    for (int j = 0; j < 4; ++j) {
      int kstep = g * 4 + j;
      afr[j] = *(const bf16x8*)&sc[c * SCW + kstep * 32 + qd * 8];
      bfr[j] = *(const bf16x8*)(vrow_ + kstep * 32 + qd * 8);
    }
#pragma unroll
    for (int j = 0; j < 4; ++j)
      oacc = __builtin_amdgcn_mfma_f32_16x16x32_bf16(afr[j], bfr[j], oacc, 0, 0, 0);
  }
#pragma unroll
  for (int i = 0; i < 4; ++i) {
    int row = qd * 4 + i;
    int srow = s0 + row;
    if (srow < S_)
      concat[((size_t)(b * S_) + srow) * NCOL + h * EOUT_ + wv_ * 16 + c] =
          oacc[i] * rs[row];
  }
}

// ---- kernel 5: wsum[b,s,t] = mpad[s,t] * sum_h rs_h[s] * exp(score_h[s,t]) ----
// R5 compute structure (batched K loads, Q dbuf, exp2f — measured 110 us) with a
// 2-D XCD partition fixing its L2 thrash (FETCH 150 MB, WRITE 112 MB measured):
// XCD x = b*2 + t-half. Per-XCD resident set: K-half 640 KB + mask-half 2 MB
// (+ 2 MB streamed output) < 4 MB L2 -> K/mask read ~once, no dirty-line churn.
// Mask read from padded mpad (aligned 1024-stride rows).
__global__ __launch_bounds__(256, 4) void wsum_kernel(
    const unsigned short* __restrict__ qbf, const unsigned short* __restrict__ kbf,
    const float* __restrict__ rsbuf, const float* __restrict__ mpad,
    float* __restrict__ out) {
  __shared__ float wrs[H_ * 16];
  int tid = threadIdx.x;
  int wv_ = tid >> 6;
  int l = tid & 63;
  int qd = l >> 4;
  int c = l & 15;
  int bid0 = blockIdx.x;
  // 1008 = 8 * 126. XCD x = (b, t-half); slot s = (tchunk-within-half, tile).
  int x_ = bid0 & 7;
  int s_ = bid0 >> 3;          // 0..125
  int b = x_ >> 1;
  int tp = x_ & 1;             // t-half
  int tile = s_ % 63;
  int tchunk = tp * 2 + (s_ / 63);  // 0..3
  int s0 = tile * 16;
  int tb = tchunk * 256 + wv_ * 64;

  if (tid < H_ * 16) {
    int hh = tid >> 4, row = tid & 15;
    wrs[tid] = rsbuf[((size_t)(b * H_ + hh) * 63 + tile) * 16 + row];
  }
  __syncthreads();

  float wacc[16];
#pragma unroll
  for (int i = 0; i < 16; ++i) wacc[i] = 0.0f;

  const size_t qoff = (size_t)(s0 + c) * EOUT_ + qd * 8;
  bf16x8 qA0, qA1, qB0, qB1;
  {
    const unsigned short* qb = qbf + (size_t)(b * H_) * SPAD * EOUT_;
    qA0 = *(const bf16x8*)(qb + qoff);
    qA1 = *(const bf16x8*)(qb + qoff + 32);
  }
#pragma unroll
  for (int h = 0; h < H_; ++h) {
    size_t bh = (size_t)(b * H_ + h);
    const unsigned short* kb = kbf + bh * SPAD * EOUT_;
    // batch all 8 K loads for this head
    bf16x8 kf0[4], kf1[4];
#pragma unroll
    for (int st = 0; st < 4; ++st) {
      const unsigned short* krow = kb + (size_t)(tb + st * 16 + c) * EOUT_ + qd * 8;
      kf0[st] = *(const bf16x8*)krow;
      kf1[st] = *(const bf16x8*)(krow + 32);
    }
    // prefetch next head's Q fragments
    if (h + 1 < H_) {
      const unsigned short* qb = qbf + (bh + 1) * SPAD * EOUT_;
      if (h & 1) {
        qA0 = *(const bf16x8*)(qb + qoff);
        qA1 = *(const bf16x8*)(qb + qoff + 32);
      } else {
        qB0 = *(const bf16x8*)(qb + qoff);
        qB1 = *(const bf16x8*)(qb + qoff + 32);
      }
    }
    bf16x8 q0 = (h & 1) ? qB0 : qA0;
    bf16x8 q1 = (h & 1) ? qB1 : qA1;
    f32x4 acc[4];
#pragma unroll
    for (int st = 0; st < 4; ++st) {
      f32x4 a = {0.f, 0.f, 0.f, 0.f};
      a = __builtin_amdgcn_mfma_f32_16x16x32_bf16(q0, kf0[st], a, 0, 0, 0);
      a = __builtin_amdgcn_mfma_f32_16x16x32_bf16(q1, kf1[st], a, 0, 0, 0);
      acc[st] = a;
    }
#pragma unroll
    for (int st = 0; st < 4; ++st)
#pragma unroll
      for (int i = 0; i < 4; ++i)
        wacc[st * 4 + i] += wrs[h * 16 + qd * 4 + i] * exp2f(acc[st][i] * C1EXP);
  }

  float* wsum = out + (size_t)B_ * S_ * NCOL;
#pragma unroll
  for (int st = 0; st < 4; ++st) {
    int t = tb + st * 16 + c;
#pragma unroll
    for (int i = 0; i < 4; ++i) {
      int srow = s0 + qd * 4 + i;
      if (srow < S_ && t < S_)
        wsum[((size_t)b * S_ + srow) * S_ + t] =
            wacc[st * 4 + i] * mpad[(size_t)srow * SPAD + t];
    }
  }
}

extern "C" void kernel_launch(void* const* d_in, const int* in_sizes, int n_in,
                              void* d_out, int out_size, void* d_ws, size_t ws_size,
                              hipStream_t stream) {
  const float* x = (const float*)d_in[0];
  const float* mask = (const float*)d_in[1];
  const float* Wq = (const float*)d_in[2];
  const float* bq = (const float*)d_in[3];
  const float* Wk = (const float*)d_in[4];
  const float* bk = (const float*)d_in[5];
  const float* Wv = (const float*)d_in[6];
  const float* bv = (const float*)d_in[7];
  float* out = (float*)d_out;

  char* ws = (char*)d_ws;
  const size_t NEED = 28308992;
  if (ws_size < NEED) return;  // fail cleanly rather than OOB
  unsigned short* xbf  = (unsigned short*)ws;              // 2,064,384 B
  unsigned short* wbf  = (unsigned short*)(ws + 2064384);  //   983,040 B
  unsigned short* qbf  = (unsigned short*)(ws + 3047424);  // 5,242,880 B
  unsigned short* kbf  = (unsigned short*)(ws + 8290304);  // 5,242,880 B
  unsigned short* vrow = (unsigned short*)(ws + 13533184); // 5,242,880 B
  unsigned short* vT   = (unsigned short*)(ws + 18776064); // 5,242,880 B
  float*          mpad = (float*)(ws + 24018944);          // 4,128,768 B
  float*          rsbuf = (float*)(ws + 28147712);         //   161,280 B

  convert_kernel<<<9984, 256, 0, stream>>>(x, Wq, Wk, Wv, mask, xbf, wbf, mpad);
  proj_kernel<<<1512, 256, 0, stream>>>(xbf, wbf, bq, bk, bv, qbf, kbf, vrow);
  transpose_v<<<640, 256, 0, stream>>>(vrow, vT);
  attn_kernel<<<2560, 256, 0, stream>>>(qbf, kbf, vT, mpad, rsbuf, out);
  wsum_kernel<<<1008, 256, 0, stream>>>(qbf, kbf, rsbuf, mpad, out);
}

// Round 10
// 233.022 us; speedup vs baseline: 1.6864x; 1.3097x over previous
//
#include <hip/hip_runtime.h>
#include <stdint.h>

#define B_ 4
#define S_ 1001
#define SP 1008    // padded rows (63 * 16)
#define SPAD 1024  // padded t dimension (32 * 32)
#define EIN_ 256
#define EOUT_ 64
#define H_ 10
#define NCOL 640   // H*EOUT
#define NCOL3 1920
#define SCW 1016   // sc row stride in bf16 (1008 cols + 8 pad)

#define C1EXP 0.090168440f  // (1/16) * log2(e): exp(s/16) = exp2(s*C1EXP)

typedef short bf16x8 __attribute__((ext_vector_type(8)));
typedef short bf16x4 __attribute__((ext_vector_type(4)));
typedef float f32x4 __attribute__((ext_vector_type(4)));

typedef unsigned int u32;
typedef __attribute__((address_space(1))) const u32* gas_ptr;
typedef __attribute__((address_space(3))) u32* las_ptr;

__device__ __forceinline__ unsigned short f2bf(float f) {
  unsigned u = __float_as_uint(f);
  u += 0x7FFFu + ((u >> 16) & 1u);  // RTNE (inputs finite)
  return (unsigned short)(u >> 16);
}
__device__ __forceinline__ float bf2f(unsigned short h) {
  return __uint_as_float(((unsigned)h) << 16);
}

// async global->LDS, 16 B per lane, no result VGPRs (compiler cannot sink it).
// LDS dest is wave-uniform base + lane*16; global src is per-lane.
__device__ __forceinline__ void stage16(const void* g, void* l) {
  __builtin_amdgcn_global_load_lds((gas_ptr)g, (las_ptr)l, 16, 0, 0);
}
#define WVM(N) asm volatile("s_waitcnt vmcnt(%0)" ::"i"(N) : "memory")
#define SB() __builtin_amdgcn_sched_barrier(0)

// ---- kernel 1: fp32 -> bf16 (x padded, W concat) + mask zero-padded fp32 ----
__global__ __launch_bounds__(256) void convert_kernel(
    const float* __restrict__ x, const float* __restrict__ Wq,
    const float* __restrict__ Wk, const float* __restrict__ Wv,
    const float* __restrict__ mask, unsigned short* __restrict__ xbf,
    unsigned short* __restrict__ wbf, float* __restrict__ mpad) {
  int i = blockIdx.x * 256 + threadIdx.x;
  const int N1 = B_ * SP * EIN_;   // 1,032,192
  const int N2 = NCOL3 * EIN_;     // 491,520
  const int N3 = SP * SPAD;        // 1,032,192
  if (i < N1) {
    int b = i / (SP * EIN_);
    int rem = i % (SP * EIN_);
    int row = rem / EIN_;
    int e = rem % EIN_;
    float v = (row < S_) ? x[((size_t)(b * S_ + row)) * EIN_ + e] : 0.0f;
    xbf[i] = f2bf(v);
  } else if (i < N1 + N2) {
    int j = i - N1;
    int col = j / EIN_;
    int e = j % EIN_;
    int mat = col / NCOL;
    int hcol = col % NCOL;
    const float* W = (mat == 0) ? Wq : (mat == 1) ? Wk : Wv;
    wbf[j] = f2bf(W[(size_t)hcol * EIN_ + e]);
  } else if (i < N1 + N2 + N3) {
    int j = i - N1 - N2;
    int row = j >> 10;
    int col = j & 1023;
    mpad[j] = (row < S_ && col < S_) ? mask[(size_t)row * S_ + col] : 0.0f;
  }
}

// ---------------- kernel 2: projection GEMM (MFMA bf16), 6-way N split ------
__global__ __launch_bounds__(256, 4) void proj_kernel(
    const unsigned short* __restrict__ xbf, const unsigned short* __restrict__ wbf,
    const float* __restrict__ bq, const float* __restrict__ bk,
    const float* __restrict__ bv, unsigned short* __restrict__ qbf,
    unsigned short* __restrict__ kbf, unsigned short* __restrict__ vrow) {
  int tid = threadIdx.x;
  int wv_ = tid >> 6;
  int l = tid & 63;
  int qd = l >> 4;
  int c = l & 15;
  int bid = blockIdx.x;
  int g = bid % 6;
  int t2 = bid / 6;
  int b = t2 / 63;
  int tile = t2 % 63;
  int s0 = tile * 16;

  bf16x8 af[8];
  const unsigned short* xrowp = xbf + (size_t)(b * SP + s0 + c) * EIN_;
#pragma unroll
  for (int ks = 0; ks < 8; ++ks)
    af[ks] = *(const bf16x8*)(xrowp + ks * 32 + qd * 8);

  for (int nt = g * 20 + wv_; nt < g * 20 + 20; nt += 4) {
    int col0 = nt * 16;
    f32x4 acc = {0.f, 0.f, 0.f, 0.f};
    const unsigned short* wrow = wbf + (size_t)(col0 + c) * EIN_;
    bf16x8 bf0[4], bf1[4];
#pragma unroll
    for (int j = 0; j < 4; ++j) bf0[j] = *(const bf16x8*)(wrow + j * 32 + qd * 8);
#pragma unroll
    for (int j = 0; j < 4; ++j) bf1[j] = *(const bf16x8*)(wrow + (4 + j) * 32 + qd * 8);
#pragma unroll
    for (int j = 0; j < 4; ++j)
      acc = __builtin_amdgcn_mfma_f32_16x16x32_bf16(af[j], bf0[j], acc, 0, 0, 0);
#pragma unroll
    for (int j = 0; j < 4; ++j)
      acc = __builtin_amdgcn_mfma_f32_16x16x32_bf16(af[4 + j], bf1[j], acc, 0, 0, 0);
    int col = col0 + c;
    int mat = col / NCOL;
    int hcol = col % NCOL;
    int hh = hcol >> 6;
    int o = hcol & 63;
    const float* bias = (mat == 0) ? bq : (mat == 1) ? bk : bv;
    float bb = bias[hcol];
    unsigned short* dst = (mat == 0) ? qbf : (mat == 1) ? kbf : vrow;
    size_t base = ((size_t)(b * H_ + hh)) * SPAD * EOUT_ + o;
#pragma unroll
    for (int i = 0; i < 4; ++i) {
      int srow = s0 + qd * 4 + i;
      float v = (srow < S_) ? (acc[i] + bb) : 0.0f;  // zero pad rows
      dst[base + (size_t)srow * EOUT_] = f2bf(v);
    }
  }
}

// ---------------- kernel 3: v [t][o] -> vT [o][t] ----------------
__global__ __launch_bounds__(256) void transpose_v(
    const unsigned short* __restrict__ vrow, unsigned short* __restrict__ vT) {
  __shared__ unsigned short tl[64 * 65];
  int bid = blockIdx.x;
  int bh = bid >> 4;
  int t0 = (bid & 15) * 64;
  int tid = threadIdx.x;
#pragma unroll
  for (int i = 0; i < 16; ++i) {
    int idx = i * 256 + tid;
    int o = idx & 63;
    int t_l = idx >> 6;
    int row = t0 + t_l;
    tl[o * 65 + t_l] =
        (row < SP) ? vrow[((size_t)bh * SPAD + row) * EOUT_ + o] : (unsigned short)0;
  }
  __syncthreads();
#pragma unroll
  for (int i = 0; i < 16; ++i) {
    int idx = i * 256 + tid;
    int t_l = idx & 63;
    int o = idx >> 6;
    vT[((size_t)bh * EOUT_ + o) * SPAD + t0 + t_l] = tl[o * 65 + t_l];
  }
}

// ---------------- kernel 4: attention — EXACT round-2 build (90.3 us) -------
__global__ __launch_bounds__(256, 4) void attn_kernel(
    const unsigned short* __restrict__ qbf, const unsigned short* __restrict__ kbf,
    const unsigned short* __restrict__ vT, const float* __restrict__ mpad,
    float* __restrict__ rsbuf, float* __restrict__ out) {
  __shared__ unsigned short sc[16 * SCW + 8];  // +8 bf16 = 16 B zero guard
  __shared__ float rs[16];

  int tid = threadIdx.x;
  int wv_ = tid >> 6;
  int l = tid & 63;
  int qd = l >> 4;
  int c = l & 15;

  int bid0 = blockIdx.x;
  int x_ = bid0 & 7;        // XCD (hw round-robins consecutive bids)
  int s_ = bid0 >> 3;       // 0..319 slot within XCD
  int xr = x_ >> 2;         // tile half (0..1)
  int xc = x_ & 3;          // bh quarter (0..3)
  int sub = s_ / 160;       // 5-bh sub-phase (0..1)
  int m_ = s_ % 160;
  int ti = m_ / 5;          // 0..31
  int bhi = m_ % 5;
  int tile = xr * 32 + ti;  // 0..63
  if (tile >= 63) return;   // 40 pad blocks
  int bh_ = xc * 10 + sub * 5 + bhi;  // 0..39
  int b = bh_ / 10;
  int h = bh_ % 10;
  int s0 = tile * 16;

  if (tid < 16) rs[tid] = 0.0f;

  float* concat = out;  // [B,S,640]

  size_t bh = (size_t)(b * H_ + h);
  const unsigned short* qb = qbf + bh * SPAD * EOUT_;
  const unsigned short* kb = kbf + bh * SPAD * EOUT_;
  const unsigned short* vb = vT + bh * EOUT_ * SPAD;

  // ---- phase A: scores = (Q K^T)/16, bf16 into LDS; batch-4 t-tiles ----
  bf16x8 aq0 = *(const bf16x8*)(qb + (size_t)(s0 + c) * EOUT_ + qd * 8);
  bf16x8 aq1 = *(const bf16x8*)(qb + (size_t)(s0 + c) * EOUT_ + 32 + qd * 8);
#pragma unroll
  for (int g = 0; g < 4; ++g) {
    bf16x8 k0[4], k1[4];
#pragma unroll
    for (int j = 0; j < 4; ++j) {
      int t0 = (wv_ + 4 * (g * 4 + j)) * 16;
      const unsigned short* krow = kb + (size_t)(t0 + c) * EOUT_ + qd * 8;
      k0[j] = *(const bf16x8*)krow;
      k1[j] = *(const bf16x8*)(krow + 32);
    }
#pragma unroll
    for (int j = 0; j < 4; ++j) {
      f32x4 acc = {0.f, 0.f, 0.f, 0.f};
      acc = __builtin_amdgcn_mfma_f32_16x16x32_bf16(aq0, k0[j], acc, 0, 0, 0);
      acc = __builtin_amdgcn_mfma_f32_16x16x32_bf16(aq1, k1[j], acc, 0, 0, 0);
      int t0 = (wv_ + 4 * (g * 4 + j)) * 16;
#pragma unroll
      for (int i = 0; i < 4; ++i)
        sc[(qd * 4 + i) * SCW + t0 + c] = f2bf(acc[i] * 0.0625f);
    }
  }
  // cols 1008..1015 of each row + the 16 B guard after row 15 must be finite
  if (tid < 128) sc[(tid >> 3) * SCW + 1008 + (tid & 7)] = 0;
  if (tid < 8) sc[16 * SCW + tid] = 0;
  __syncthreads();

  // ---- phase B: row-per-wave; l = exp(s)*mask, rs per row; hoisted loads ----
#pragma unroll
  for (int rr = 0; rr < 4; ++rr) {
    int r = wv_ * 4 + rr;
    int srow = s0 + r;
    if (srow < S_) {
      const float* mrow = mpad + (size_t)srow * SPAD;
      bf16x4 sv[4];
      f32x4 mv[4];
      bool tail = (l < 60);
#pragma unroll
      for (int ci = 0; ci < 3; ++ci) {
        int t0c = ci * 256 + 4 * l;
        sv[ci] = *(const bf16x4*)&sc[r * SCW + t0c];
        mv[ci] = *(const f32x4*)(mrow + t0c);
      }
      if (tail) {
        int t0c = 768 + 4 * l;
        sv[3] = *(const bf16x4*)&sc[r * SCW + t0c];
        mv[3] = *(const f32x4*)(mrow + t0c);
      }
      float nacc = 0.0f;
#pragma unroll
      for (int ci = 0; ci < 3; ++ci) {
        int t0c = ci * 256 + 4 * l;
        bf16x4 lvv;
#pragma unroll
        for (int j = 0; j < 4; ++j) {
          float e = __expf(bf2f((unsigned short)sv[ci][j]));
          float lval = e * mv[ci][j];  // mpad pad cols are 0 -> lval 0
          nacc += lval * lval;
          lvv[j] = (short)f2bf(lval);
        }
        *(bf16x4*)&sc[r * SCW + t0c] = lvv;
      }
      if (tail) {  // tail chunk: cols 768..1007
        int t0c = 768 + 4 * l;
        bf16x4 lvv;
#pragma unroll
        for (int j = 0; j < 4; ++j) {
          float e = __expf(bf2f((unsigned short)sv[3][j]));
          float lval = e * mv[3][j];
          nacc += lval * lval;
          lvv[j] = (short)f2bf(lval);
        }
        *(bf16x4*)&sc[r * SCW + t0c] = lvv;
      }
      nacc += __shfl_xor(nacc, 1);
      nacc += __shfl_xor(nacc, 2);
      nacc += __shfl_xor(nacc, 4);
      nacc += __shfl_xor(nacc, 8);
      nacc += __shfl_xor(nacc, 16);
      nacc += __shfl_xor(nacc, 32);
      if (l == 0) rs[r] = 1.0f / fmaxf(sqrtf(nacc), 1e-12f);
    }
  }
  __syncthreads();

  if (tid < 16) rsbuf[((size_t)bh * 63 + tile) * 16 + tid] = rs[tid];

  // ---- phase D: out = (l V) * rs[row]; batch-4 ksteps ----
  f32x4 oacc = {0.f, 0.f, 0.f, 0.f};
  const unsigned short* vrow_ = vb + (size_t)(wv_ * 16 + c) * SPAD;
#pragma unroll
  for (int g = 0; g < 8; ++g) {
    bf16x8 afr[4], bfr[4];
#pragma unroll
    for (int j = 0; j < 4; ++j) {
      int kstep = g * 4 + j;
      afr[j] = *(const bf16x8*)&sc[c * SCW + kstep * 32 + qd * 8];
      bfr[j] = *(const bf16x8*)(vrow_ + kstep * 32 + qd * 8);
    }
#pragma unroll
    for (int j = 0; j < 4; ++j)
      oacc = __builtin_amdgcn_mfma_f32_16x16x32_bf16(afr[j], bfr[j], oacc, 0, 0, 0);
  }
#pragma unroll
  for (int i = 0; i < 4; ++i) {
    int row = qd * 4 + i;
    int srow = s0 + row;
    if (srow < S_)
      concat[((size_t)(b * S_) + srow) * NCOL + h * EOUT_ + wv_ * 16 + c] =
          oacc[i] * rs[row];
  }
}

// ---- kernel 5: wsum via async LDS-staged K pipeline ----
// wsum[b,s,t] = mpad[s,t] * sum_h rs_h[s] * exp2(score*C1EXP).
// Each wave owns a private 64-row K strip per head; K is staged into LDS with
// global_load_lds (async, no result VGPRs -> compiler cannot serialize it),
// double-buffered in 32-row half-heads (m = h*2+p, 20 steps). Counted
// s_waitcnt vmcnt(4) + sched_barrier(0) per step; never drains mid-loop; no
// barriers in the loop (wave-private staging). K garbage rows >=1008 stay
// per-lane isolated and are discarded by the t<S_ store guard.
__global__ __launch_bounds__(256) void wsum_kernel(
    const unsigned short* __restrict__ qbf, const unsigned short* __restrict__ kbf,
    const float* __restrict__ rsbuf, const float* __restrict__ mpad,
    float* __restrict__ out) {
  __shared__ unsigned short kst[2][4][32 * 64];  // 32 KB: [buf][wave][row*64+col]
  __shared__ float wrs[H_ * 16];
  int tid = threadIdx.x;
  int wv_ = tid >> 6;
  int l = tid & 63;
  int qd = l >> 4;
  int c = l & 15;
  int lrow = l >> 3;  // staging: lane covers row lrow, 16B-block lblk
  int lblk = l & 7;
  int bid0 = blockIdx.x;
  // XCD swizzle: 1008 = 8 * 126; co-locate same-tile blocks per XCD.
  int bid = (bid0 & 7) * 126 + (bid0 >> 3);
  int tchunk = bid & 3;
  int rem = bid >> 2;
  int tile = rem % 63;
  int b = rem / 63;
  int s0 = tile * 16;
  int tb = tchunk * 256 + wv_ * 64;

  if (tid < H_ * 16) {
    int hh = tid >> 4, row = tid & 15;
    wrs[tid] = rsbuf[((size_t)(b * H_ + hh) * 63 + tile) * 16 + row];
  }
  __syncthreads();  // before any staging: barrier's vmcnt drain is harmless here

  const unsigned short* kbase = kbf + (size_t)(b * H_) * SPAD * EOUT_;
  const unsigned short* qbase = qbf + (size_t)(b * H_) * SPAD * EOUT_;
  const size_t qoff = (size_t)(s0 + c) * EOUT_ + qd * 8;

  // stage half-head M (head M>>1, rows [(M&1)*32, +32) of this wave's strip)
#define STAGE_HALF(M)                                                         \
  do {                                                                        \
    int h_ = (M) >> 1, p_ = (M) & 1;                                          \
    const unsigned short* kb_ = kbase + (size_t)h_ * SPAD * EOUT_;            \
    unsigned short* dst_ = &kst[(M) & 1][wv_][0];                             \
    _Pragma("unroll") for (int i_ = 0; i_ < 4; ++i_) {                        \
      int r_ = p_ * 32 + i_ * 8 + lrow;                                       \
      stage16(kb_ + (size_t)(tb + r_) * EOUT_ + lblk * 8, dst_ + i_ * 512);   \
    }                                                                         \
  } while (0)

  float wacc[16];
#pragma unroll
  for (int i = 0; i < 16; ++i) wacc[i] = 0.0f;

  STAGE_HALF(0);
  STAGE_HALF(1);

  bf16x8 q0, q1;
  for (int m = 0; m < 20; ++m) {
    int h = m >> 1;
    int p = m & 1;
    if (p == 0) {  // Q fragments for this head (compiler-managed latency)
      const unsigned short* qb = qbase + (size_t)h * SPAD * EOUT_;
      q0 = *(const bf16x8*)(qb + qoff);
      q1 = *(const bf16x8*)(qb + qoff + 32);
    }
    if (m < 19) {
      WVM(4);  // half m done (>=4 younger stage ops follow it in the queue)
    } else {
      WVM(0);
    }
    SB();  // nothing (esp. the ds_reads below) may hoist above the wait
    const unsigned short* kl = &kst[m & 1][wv_][0];
#pragma unroll
    for (int sp = 0; sp < 2; ++sp) {
      int st = p * 2 + sp;
      int rh = sp * 16 + c;  // row within the 32-row half
      const unsigned short* kr = kl + rh * 64 + qd * 8;
      bf16x8 k0 = *(const bf16x8*)kr;
      bf16x8 k1 = *(const bf16x8*)(kr + 32);
      f32x4 a = {0.f, 0.f, 0.f, 0.f};
      a = __builtin_amdgcn_mfma_f32_16x16x32_bf16(q0, k0, a, 0, 0, 0);
      a = __builtin_amdgcn_mfma_f32_16x16x32_bf16(q1, k1, a, 0, 0, 0);
#pragma unroll
      for (int i = 0; i < 4; ++i)
        wacc[st * 4 + i] += wrs[h * 16 + qd * 4 + i] * exp2f(a[i] * C1EXP);
    }
    if (m < 18) STAGE_HALF(m + 2);
  }

  float* wsum = out + (size_t)B_ * S_ * NCOL;
#pragma unroll
  for (int st = 0; st < 4; ++st) {
    int t = tb + st * 16 + c;
#pragma unroll
    for (int i = 0; i < 4; ++i) {
      int srow = s0 + qd * 4 + i;
      if (srow < S_ && t < S_)
        wsum[((size_t)b * S_ + srow) * S_ + t] =
            wacc[st * 4 + i] * mpad[(size_t)srow * SPAD + t];
    }
  }
#undef STAGE_HALF
}

extern "C" void kernel_launch(void* const* d_in, const int* in_sizes, int n_in,
                              void* d_out, int out_size, void* d_ws, size_t ws_size,
                              hipStream_t stream) {
  const float* x = (const float*)d_in[0];
  const float* mask = (const float*)d_in[1];
  const float* Wq = (const float*)d_in[2];
  const float* bq = (const float*)d_in[3];
  const float* Wk = (const float*)d_in[4];
  const float* bk = (const float*)d_in[5];
  const float* Wv = (const float*)d_in[6];
  const float* bv = (const float*)d_in[7];
  float* out = (float*)d_out;

  char* ws = (char*)d_ws;
  const size_t NEED = 28308992;
  if (ws_size < NEED) return;  // fail cleanly rather than OOB
  unsigned short* xbf  = (unsigned short*)ws;              // 2,064,384 B
  unsigned short* wbf  = (unsigned short*)(ws + 2064384);  //   983,040 B
  unsigned short* qbf  = (unsigned short*)(ws + 3047424);  // 5,242,880 B
  unsigned short* kbf  = (unsigned short*)(ws + 8290304);  // 5,242,880 B
  unsigned short* vrow = (unsigned short*)(ws + 13533184); // 5,242,880 B
  unsigned short* vT   = (unsigned short*)(ws + 18776064); // 5,242,880 B
  float*          mpad = (float*)(ws + 24018944);          // 4,128,768 B
  float*          rsbuf = (float*)(ws + 28147712);         //   161,280 B

  convert_kernel<<<9984, 256, 0, stream>>>(x, Wq, Wk, Wv, mask, xbf, wbf, mpad);
  proj_kernel<<<1512, 256, 0, stream>>>(xbf, wbf, bq, bk, bv, qbf, kbf, vrow);
  transpose_v<<<640, 256, 0, stream>>>(vrow, vT);
  attn_kernel<<<2560, 256, 0, stream>>>(qbf, kbf, vT, mpad, rsbuf, out);
  wsum_kernel<<<1008, 256, 0, stream>>>(qbf, kbf, rsbuf, mpad, out);
}

// Round 12
// 209.868 us; speedup vs baseline: 1.8724x; 1.1103x over previous
//
#include <hip/hip_runtime.h>
#include <stdint.h>

#define B_ 4
#define S_ 1001
#define SP 1008    // padded rows (63 * 16)
#define SPAD 1024  // padded t dimension (32 * 32)
#define EIN_ 256
#define EOUT_ 64
#define H_ 10
#define NCOL 640   // H*EOUT
#define NCOL3 1920
#define SCW 1016   // sc row stride in bf16 (1008 cols + 8 pad)

#define C1EXP 0.090168440f  // (1/16) * log2(e): exp(s/16) = exp2(s*C1EXP)

typedef short bf16x8 __attribute__((ext_vector_type(8)));
typedef short bf16x4 __attribute__((ext_vector_type(4)));
typedef float f32x4 __attribute__((ext_vector_type(4)));

typedef unsigned int u32;
typedef __attribute__((address_space(1))) const u32* gas_ptr;
typedef __attribute__((address_space(3))) u32* las_ptr;

__device__ __forceinline__ unsigned short f2bf(float f) {
  unsigned u = __float_as_uint(f);
  u += 0x7FFFu + ((u >> 16) & 1u);  // RTNE (inputs finite)
  return (unsigned short)(u >> 16);
}
__device__ __forceinline__ float bf2f(unsigned short h) {
  return __uint_as_float(((unsigned)h) << 16);
}

// async global->LDS, 16 B per lane, no result VGPRs (compiler cannot sink it).
// LDS dest is wave-uniform base + lane*16; global src is per-lane.
__device__ __forceinline__ void stage16(const void* g, void* l) {
  __builtin_amdgcn_global_load_lds((gas_ptr)g, (las_ptr)l, 16, 0, 0);
}
#define WVM(N) asm volatile("s_waitcnt vmcnt(%0)" ::"i"(N) : "memory")
#define SB() __builtin_amdgcn_sched_barrier(0)
// read-fence: all prior ds_reads complete before anything below issues.
// Closes the WAR window where the next STAGE's async LDS-write could land in
// the buffer the current iteration's ds_reads are still consuming (R11 bug).
#define FENCE_RW()                                       \
  do {                                                   \
    asm volatile("s_waitcnt lgkmcnt(0)" ::: "memory");   \
    __builtin_amdgcn_sched_barrier(0);                   \
  } while (0)

// ---- kernel 1: fp32 -> bf16 (x padded, W concat) + mask zero-padded fp32 ----
__global__ __launch_bounds__(256) void convert_kernel(
    const float* __restrict__ x, const float* __restrict__ Wq,
    const float* __restrict__ Wk, const float* __restrict__ Wv,
    const float* __restrict__ mask, unsigned short* __restrict__ xbf,
    unsigned short* __restrict__ wbf, float* __restrict__ mpad) {
  int i = blockIdx.x * 256 + threadIdx.x;
  const int N1 = B_ * SP * EIN_;   // 1,032,192
  const int N2 = NCOL3 * EIN_;     // 491,520
  const int N3 = SP * SPAD;        // 1,032,192
  if (i < N1) {
    int b = i / (SP * EIN_);
    int rem = i % (SP * EIN_);
    int row = rem / EIN_;
    int e = rem % EIN_;
    float v = (row < S_) ? x[((size_t)(b * S_ + row)) * EIN_ + e] : 0.0f;
    xbf[i] = f2bf(v);
  } else if (i < N1 + N2) {
    int j = i - N1;
    int col = j / EIN_;
    int e = j % EIN_;
    int mat = col / NCOL;
    int hcol = col % NCOL;
    const float* W = (mat == 0) ? Wq : (mat == 1) ? Wk : Wv;
    wbf[j] = f2bf(W[(size_t)hcol * EIN_ + e]);
  } else if (i < N1 + N2 + N3) {
    int j = i - N1 - N2;
    int row = j >> 10;
    int col = j & 1023;
    mpad[j] = (row < S_ && col < S_) ? mask[(size_t)row * S_ + col] : 0.0f;
  }
}

// ---------------- kernel 2: projection GEMM (MFMA bf16), 6-way N split ------
__global__ __launch_bounds__(256, 4) void proj_kernel(
    const unsigned short* __restrict__ xbf, const unsigned short* __restrict__ wbf,
    const float* __restrict__ bq, const float* __restrict__ bk,
    const float* __restrict__ bv, unsigned short* __restrict__ qbf,
    unsigned short* __restrict__ kbf, unsigned short* __restrict__ vrow) {
  int tid = threadIdx.x;
  int wv_ = tid >> 6;
  int l = tid & 63;
  int qd = l >> 4;
  int c = l & 15;
  int bid = blockIdx.x;
  int g = bid % 6;
  int t2 = bid / 6;
  int b = t2 / 63;
  int tile = t2 % 63;
  int s0 = tile * 16;

  bf16x8 af[8];
  const unsigned short* xrowp = xbf + (size_t)(b * SP + s0 + c) * EIN_;
#pragma unroll
  for (int ks = 0; ks < 8; ++ks)
    af[ks] = *(const bf16x8*)(xrowp + ks * 32 + qd * 8);

  for (int nt = g * 20 + wv_; nt < g * 20 + 20; nt += 4) {
    int col0 = nt * 16;
    f32x4 acc = {0.f, 0.f, 0.f, 0.f};
    const unsigned short* wrow = wbf + (size_t)(col0 + c) * EIN_;
    bf16x8 bf0[4], bf1[4];
#pragma unroll
    for (int j = 0; j < 4; ++j) bf0[j] = *(const bf16x8*)(wrow + j * 32 + qd * 8);
#pragma unroll
    for (int j = 0; j < 4; ++j) bf1[j] = *(const bf16x8*)(wrow + (4 + j) * 32 + qd * 8);
#pragma unroll
    for (int j = 0; j < 4; ++j)
      acc = __builtin_amdgcn_mfma_f32_16x16x32_bf16(af[j], bf0[j], acc, 0, 0, 0);
#pragma unroll
    for (int j = 0; j < 4; ++j)
      acc = __builtin_amdgcn_mfma_f32_16x16x32_bf16(af[4 + j], bf1[j], acc, 0, 0, 0);
    int col = col0 + c;
    int mat = col / NCOL;
    int hcol = col % NCOL;
    int hh = hcol >> 6;
    int o = hcol & 63;
    const float* bias = (mat == 0) ? bq : (mat == 1) ? bk : bv;
    float bb = bias[hcol];
    unsigned short* dst = (mat == 0) ? qbf : (mat == 1) ? kbf : vrow;
    size_t base = ((size_t)(b * H_ + hh)) * SPAD * EOUT_ + o;
#pragma unroll
    for (int i = 0; i < 4; ++i) {
      int srow = s0 + qd * 4 + i;
      float v = (srow < S_) ? (acc[i] + bb) : 0.0f;  // zero pad rows
      dst[base + (size_t)srow * EOUT_] = f2bf(v);
    }
  }
}

// ---------------- kernel 3: v [t][o] -> vT [o][t] ----------------
__global__ __launch_bounds__(256) void transpose_v(
    const unsigned short* __restrict__ vrow, unsigned short* __restrict__ vT) {
  __shared__ unsigned short tl[64 * 65];
  int bid = blockIdx.x;
  int bh = bid >> 4;
  int t0 = (bid & 15) * 64;
  int tid = threadIdx.x;
#pragma unroll
  for (int i = 0; i < 16; ++i) {
    int idx = i * 256 + tid;
    int o = idx & 63;
    int t_l = idx >> 6;
    int row = t0 + t_l;
    tl[o * 65 + t_l] =
        (row < SP) ? vrow[((size_t)bh * SPAD + row) * EOUT_ + o] : (unsigned short)0;
  }
  __syncthreads();
#pragma unroll
  for (int i = 0; i < 16; ++i) {
    int idx = i * 256 + tid;
    int t_l = idx & 63;
    int o = idx >> 6;
    vT[((size_t)bh * EOUT_ + o) * SPAD + t0 + t_l] = tl[o * 65 + t_l];
  }
}

// ---------------- kernel 4: attention with async-staged K and V -------------
// R11 structure + FENCE_RW in both staged loops (the R11 accuracy bug was the
// unfenced WAR: STAGE(idx+2) overwrites kst[idx&1] while iteration idx's
// ds_reads may still be outstanding). LDS: sc 32528 + rs 64 + kst 16384 =
// 48976 B -> 3 blocks/CU (= measured residency of the R2 build).
__global__ __launch_bounds__(256) void attn_kernel(
    const unsigned short* __restrict__ qbf, const unsigned short* __restrict__ kbf,
    const unsigned short* __restrict__ vT, const float* __restrict__ mpad,
    float* __restrict__ rsbuf, float* __restrict__ out) {
  __shared__ __align__(16) unsigned short kst[2][4][16 * 64];  // 16 KB staging
  __shared__ unsigned short sc[16 * SCW + 8];  // +8 bf16 = 16 B zero guard
  __shared__ float rs[16];

  int tid = threadIdx.x;
  int wv_ = tid >> 6;
  int l = tid & 63;
  int qd = l >> 4;
  int c = l & 15;

  int bid0 = blockIdx.x;
  int x_ = bid0 & 7;        // XCD (hw round-robins consecutive bids)
  int s_ = bid0 >> 3;       // 0..319 slot within XCD
  int xr = x_ >> 2;         // tile half (0..1)
  int xc = x_ & 3;          // bh quarter (0..3)
  int sub = s_ / 160;       // 5-bh sub-phase (0..1)
  int m_ = s_ % 160;
  int ti = m_ / 5;          // 0..31
  int bhi = m_ % 5;
  int tile = xr * 32 + ti;  // 0..63
  if (tile >= 63) return;   // 40 pad blocks (uniform, before any barrier)
  int bh_ = xc * 10 + sub * 5 + bhi;  // 0..39
  int b = bh_ / 10;
  int h = bh_ % 10;
  int s0 = tile * 16;

  if (tid < 16) rs[tid] = 0.0f;

  float* concat = out;  // [B,S,640]

  size_t bh = (size_t)(b * H_ + h);
  const unsigned short* qb = qbf + bh * SPAD * EOUT_;
  const unsigned short* kb = kbf + bh * SPAD * EOUT_;
  const unsigned short* vb = vT + bh * EOUT_ * SPAD;

  bf16x8 aq0 = *(const bf16x8*)(qb + (size_t)(s0 + c) * EOUT_ + qd * 8);
  bf16x8 aq1 = *(const bf16x8*)(qb + (size_t)(s0 + c) * EOUT_ + 32 + qd * 8);

  // stage K tile idx (rows t0..t0+15, all 64 cols) into kst[idx&1][wv_]:
  // op i_: lane l covers 16B-block j=i_*64+l -> row j>>3, col-block j&7.
#define STAGE_K(IDX)                                                          \
  do {                                                                        \
    int t0_ = (wv_ + 4 * (IDX)) * 16;                                         \
    const unsigned short* src_ = kb + (size_t)t0_ * EOUT_;                    \
    unsigned short* dst_ = &kst[(IDX) & 1][wv_][0];                           \
    stage16(src_ + (size_t)(l >> 3) * EOUT_ + (l & 7) * 8, dst_);             \
    stage16(src_ + (size_t)(8 + (l >> 3)) * EOUT_ + (l & 7) * 8, dst_ + 512); \
  } while (0)

  // ---- phase A: scores = (Q K^T)/16 via staged K pipeline ----
  STAGE_K(0);
  STAGE_K(1);
#pragma unroll
  for (int idx = 0; idx < 16; ++idx) {
    if (idx < 15) {
      WVM(2);  // tile idx landed (only tile idx+1's 2 ops may remain)
    } else {
      WVM(0);
    }
    SB();  // ds_reads below must not hoist above the wait
    if (wv_ < 3 || idx < 15) {  // wv_=3,idx=15 is the pad tile (race fix)
      int t0 = (wv_ + 4 * idx) * 16;
      const unsigned short* kl = &kst[idx & 1][wv_][0];
      bf16x8 k0 = *(const bf16x8*)(kl + c * 64 + qd * 8);
      bf16x8 k1 = *(const bf16x8*)(kl + c * 64 + qd * 8 + 32);
      f32x4 acc = {0.f, 0.f, 0.f, 0.f};
      acc = __builtin_amdgcn_mfma_f32_16x16x32_bf16(aq0, k0, acc, 0, 0, 0);
      acc = __builtin_amdgcn_mfma_f32_16x16x32_bf16(aq1, k1, acc, 0, 0, 0);
#pragma unroll
      for (int i = 0; i < 4; ++i)
        sc[(qd * 4 + i) * SCW + t0 + c] = f2bf(acc[i] * 0.0625f);
    }
    FENCE_RW();  // ds_reads (and sc writes) complete before next stage issues
    if (idx < 14) STAGE_K(idx + 2);
  }
  // cols 1008..1015 of each row + the 16 B guard after row 15 must be finite
  if (tid < 128) sc[(tid >> 3) * SCW + 1008 + (tid & 7)] = 0;
  if (tid < 8) sc[16 * SCW + tid] = 0;
  __syncthreads();

  // ---- phase B: row-per-wave; l = exp(s)*mask, rs per row; hoisted loads ----
#pragma unroll
  for (int rr = 0; rr < 4; ++rr) {
    int r = wv_ * 4 + rr;
    int srow = s0 + r;
    if (srow < S_) {
      const float* mrow = mpad + (size_t)srow * SPAD;
      bf16x4 sv[4];
      f32x4 mv[4];
      bool tail = (l < 60);
#pragma unroll
      for (int ci = 0; ci < 3; ++ci) {
        int t0c = ci * 256 + 4 * l;
        sv[ci] = *(const bf16x4*)&sc[r * SCW + t0c];
        mv[ci] = *(const f32x4*)(mrow + t0c);
      }
      if (tail) {
        int t0c = 768 + 4 * l;
        sv[3] = *(const bf16x4*)&sc[r * SCW + t0c];
        mv[3] = *(const f32x4*)(mrow + t0c);
      }
      float nacc = 0.0f;
#pragma unroll
      for (int ci = 0; ci < 3; ++ci) {
        int t0c = ci * 256 + 4 * l;
        bf16x4 lvv;
#pragma unroll
        for (int j = 0; j < 4; ++j) {
          float e = __expf(bf2f((unsigned short)sv[ci][j]));
          float lval = e * mv[ci][j];  // mpad pad cols are 0 -> lval 0
          nacc += lval * lval;
          lvv[j] = (short)f2bf(lval);
        }
        *(bf16x4*)&sc[r * SCW + t0c] = lvv;
      }
      if (tail) {  // tail chunk: cols 768..1007
        int t0c = 768 + 4 * l;
        bf16x4 lvv;
#pragma unroll
        for (int j = 0; j < 4; ++j) {
          float e = __expf(bf2f((unsigned short)sv[3][j]));
          float lval = e * mv[3][j];
          nacc += lval * lval;
          lvv[j] = (short)f2bf(lval);
        }
        *(bf16x4*)&sc[r * SCW + t0c] = lvv;
      }
      nacc += __shfl_xor(nacc, 1);
      nacc += __shfl_xor(nacc, 2);
      nacc += __shfl_xor(nacc, 4);
      nacc += __shfl_xor(nacc, 8);
      nacc += __shfl_xor(nacc, 16);
      nacc += __shfl_xor(nacc, 32);
      if (l == 0) rs[r] = 1.0f / fmaxf(sqrtf(nacc), 1e-12f);
    }
  }
  __syncthreads();

  if (tid < 16) rsbuf[((size_t)bh * 63 + tile) * 16 + tid] = rs[tid];

  // ---- phase D: out = (loc V) * rs[row] via staged V pipeline ----
  // V granule p = 64 cols (2 ksteps) of this wave's 16-row strip; reuses kst
  // (phase A's stage ops fully drained by the barrier's vmcnt(0)).
#define STAGE_V(P)                                                            \
  do {                                                                        \
    const unsigned short* src_ = vb + (size_t)(wv_ * 16) * SPAD + (P) * 64;   \
    unsigned short* dst_ = &kst[(P) & 1][wv_][0];                             \
    stage16(src_ + (size_t)(l >> 3) * SPAD + (l & 7) * 8, dst_);              \
    stage16(src_ + (size_t)(8 + (l >> 3)) * SPAD + (l & 7) * 8, dst_ + 512);  \
  } while (0)

  f32x4 oacc = {0.f, 0.f, 0.f, 0.f};
  const unsigned short* scrow = &sc[c * SCW + qd * 8];
  STAGE_V(0);
  STAGE_V(1);
#pragma unroll
  for (int p = 0; p < 16; ++p) {
    if (p < 15) {
      WVM(2);
    } else {
      WVM(0);
    }
    SB();
    const unsigned short* kl = &kst[p & 1][wv_][0];
#pragma unroll
    for (int sp = 0; sp < 2; ++sp) {
      int kstep = p * 2 + sp;
      bf16x8 a = *(const bf16x8*)(scrow + (size_t)kstep * 32);
      bf16x8 v = *(const bf16x8*)(kl + c * 64 + sp * 32 + qd * 8);
      oacc = __builtin_amdgcn_mfma_f32_16x16x32_bf16(a, v, oacc, 0, 0, 0);
    }
    FENCE_RW();  // kst/sc ds_reads complete before next stage issues
    if (p < 14) STAGE_V(p + 2);
  }
#pragma unroll
  for (int i = 0; i < 4; ++i) {
    int row = qd * 4 + i;
    int srow = s0 + row;
    if (srow < S_)
      concat[((size_t)(b * S_) + srow) * NCOL + h * EOUT_ + wv_ * 16 + c] =
          oacc[i] * rs[row];
  }
#undef STAGE_K
#undef STAGE_V
}

// ---- kernel 5: wsum via async LDS-staged K pipeline [R10 + FENCE_RW] ----
__global__ __launch_bounds__(256) void wsum_kernel(
    const unsigned short* __restrict__ qbf, const unsigned short* __restrict__ kbf,
    const float* __restrict__ rsbuf, const float* __restrict__ mpad,
    float* __restrict__ out) {
  __shared__ unsigned short kst[2][4][32 * 64];  // 32 KB: [buf][wave][row*64+col]
  __shared__ float wrs[H_ * 16];
  int tid = threadIdx.x;
  int wv_ = tid >> 6;
  int l = tid & 63;
  int qd = l >> 4;
  int c = l & 15;
  int lrow = l >> 3;  // staging: lane covers row lrow, 16B-block lblk
  int lblk = l & 7;
  int bid0 = blockIdx.x;
  // XCD swizzle: 1008 = 8 * 126; co-locate same-tile blocks per XCD.
  int bid = (bid0 & 7) * 126 + (bid0 >> 3);
  int tchunk = bid & 3;
  int rem = bid >> 2;
  int tile = rem % 63;
  int b = rem / 63;
  int s0 = tile * 16;
  int tb = tchunk * 256 + wv_ * 64;

  if (tid < H_ * 16) {
    int hh = tid >> 4, row = tid & 15;
    wrs[tid] = rsbuf[((size_t)(b * H_ + hh) * 63 + tile) * 16 + row];
  }
  __syncthreads();  // before any staging: barrier's vmcnt drain is harmless here

  const unsigned short* kbase = kbf + (size_t)(b * H_) * SPAD * EOUT_;
  const unsigned short* qbase = qbf + (size_t)(b * H_) * SPAD * EOUT_;
  const size_t qoff = (size_t)(s0 + c) * EOUT_ + qd * 8;

  // stage half-head M (head M>>1, rows [(M&1)*32, +32) of this wave's strip)
#define STAGE_HALF(M)                                                         \
  do {                                                                        \
    int h_ = (M) >> 1, p_ = (M) & 1;                                          \
    const unsigned short* kb_ = kbase + (size_t)h_ * SPAD * EOUT_;            \
    unsigned short* dst_ = &kst[(M) & 1][wv_][0];                             \
    _Pragma("unroll") for (int i_ = 0; i_ < 4; ++i_) {                        \
      int r_ = p_ * 32 + i_ * 8 + lrow;                                       \
      stage16(kb_ + (size_t)(tb + r_) * EOUT_ + lblk * 8, dst_ + i_ * 512);   \
    }                                                                         \
  } while (0)

  float wacc[16];
#pragma unroll
  for (int i = 0; i < 16; ++i) wacc[i] = 0.0f;

  STAGE_HALF(0);
  STAGE_HALF(1);

  bf16x8 q0, q1;
  for (int m = 0; m < 20; ++m) {
    int h = m >> 1;
    int p = m & 1;
    if (p == 0) {  // Q fragments for this head (compiler-managed latency)
      const unsigned short* qb = qbase + (size_t)h * SPAD * EOUT_;
      q0 = *(const bf16x8*)(qb + qoff);
      q1 = *(const bf16x8*)(qb + qoff + 32);
    }
    if (m < 19) {
      WVM(4);  // half m done (>=4 younger stage ops follow it in the queue)
    } else {
      WVM(0);
    }
    SB();  // nothing (esp. the ds_reads below) may hoist above the wait
    const unsigned short* kl = &kst[m & 1][wv_][0];
#pragma unroll
    for (int sp = 0; sp < 2; ++sp) {
      int st = p * 2 + sp;
      int rh = sp * 16 + c;  // row within the 32-row half
      const unsigned short* kr = kl + rh * 64 + qd * 8;
      bf16x8 k0 = *(const bf16x8*)kr;
      bf16x8 k1 = *(const bf16x8*)(kr + 32);
      f32x4 a = {0.f, 0.f, 0.f, 0.f};
      a = __builtin_amdgcn_mfma_f32_16x16x32_bf16(q0, k0, a, 0, 0, 0);
      a = __builtin_amdgcn_mfma_f32_16x16x32_bf16(q1, k1, a, 0, 0, 0);
#pragma unroll
      for (int i = 0; i < 4; ++i)
        wacc[st * 4 + i] += wrs[h * 16 + qd * 4 + i] * exp2f(a[i] * C1EXP);
    }
    FENCE_RW();  // kst ds_reads complete before next stage issues (WAR fix)
    if (m < 18) STAGE_HALF(m + 2);
  }

  float* wsum = out + (size_t)B_ * S_ * NCOL;
#pragma unroll
  for (int st = 0; st < 4; ++st) {
    int t = tb + st * 16 + c;
#pragma unroll
    for (int i = 0; i < 4; ++i) {
      int srow = s0 + qd * 4 + i;
      if (srow < S_ && t < S_)
        wsum[((size_t)b * S_ + srow) * S_ + t] =
            wacc[st * 4 + i] * mpad[(size_t)srow * SPAD + t];
    }
  }
#undef STAGE_HALF
}

extern "C" void kernel_launch(void* const* d_in, const int* in_sizes, int n_in,
                              void* d_out, int out_size, void* d_ws, size_t ws_size,
                              hipStream_t stream) {
  const float* x = (const float*)d_in[0];
  const float* mask = (const float*)d_in[1];
  const float* Wq = (const float*)d_in[2];
  const float* bq = (const float*)d_in[3];
  const float* Wk = (const float*)d_in[4];
  const float* bk = (const float*)d_in[5];
  const float* Wv = (const float*)d_in[6];
  const float* bv = (const float*)d_in[7];
  float* out = (float*)d_out;

  char* ws = (char*)d_ws;
  const size_t NEED = 28308992;
  if (ws_size < NEED) return;  // fail cleanly rather than OOB
  unsigned short* xbf  = (unsigned short*)ws;              // 2,064,384 B
  unsigned short* wbf  = (unsigned short*)(ws + 2064384);  //   983,040 B
  unsigned short* qbf  = (unsigned short*)(ws + 3047424);  // 5,242,880 B
  unsigned short* kbf  = (unsigned short*)(ws + 8290304);  // 5,242,880 B
  unsigned short* vrow = (unsigned short*)(ws + 13533184); // 5,242,880 B
  unsigned short* vT   = (unsigned short*)(ws + 18776064); // 5,242,880 B
  float*          mpad = (float*)(ws + 24018944);          // 4,128,768 B
  float*          rsbuf = (float*)(ws + 28147712);         //   161,280 B

  convert_kernel<<<9984, 256, 0, stream>>>(x, Wq, Wk, Wv, mask, xbf, wbf, mpad);
  proj_kernel<<<1512, 256, 0, stream>>>(xbf, wbf, bq, bk, bv, qbf, kbf, vrow);
  transpose_v<<<640, 256, 0, stream>>>(vrow, vT);
  attn_kernel<<<2560, 256, 0, stream>>>(qbf, kbf, vT, mpad, rsbuf, out);
  wsum_kernel<<<1008, 256, 0, stream>>>(qbf, kbf, rsbuf, mpad, out);
}

// Round 13
// 207.070 us; speedup vs baseline: 1.8977x; 1.0135x over previous
//
#include <hip/hip_runtime.h>
#include <stdint.h>

#define B_ 4
#define S_ 1001
#define SP 1008    // padded rows (63 * 16)
#define SPAD 1024  // padded t dimension (32 * 32)
#define EIN_ 256
#define EOUT_ 64
#define H_ 10
#define NCOL 640   // H*EOUT
#define NCOL3 1920
#define SCW 1016   // sc row stride in bf16 (1008 cols + 8 pad)

#define C1EXP 0.090168440f  // (1/16) * log2(e): exp(s/16) = exp2(s*C1EXP)

typedef short bf16x8 __attribute__((ext_vector_type(8)));
typedef short bf16x4 __attribute__((ext_vector_type(4)));
typedef float f32x4 __attribute__((ext_vector_type(4)));

typedef unsigned int u32;
typedef __attribute__((address_space(1))) const u32* gas_ptr;
typedef __attribute__((address_space(3))) u32* las_ptr;

__device__ __forceinline__ unsigned short f2bf(float f) {
  unsigned u = __float_as_uint(f);
  u += 0x7FFFu + ((u >> 16) & 1u);  // RTNE (inputs finite)
  return (unsigned short)(u >> 16);
}
__device__ __forceinline__ float bf2f(unsigned short h) {
  return __uint_as_float(((unsigned)h) << 16);
}

// async global->LDS, 16 B per lane, no result VGPRs (compiler cannot sink it).
// LDS dest is wave-uniform base + lane*16; global src is per-lane.
__device__ __forceinline__ void stage16(const void* g, void* l) {
  __builtin_amdgcn_global_load_lds((gas_ptr)g, (las_ptr)l, 16, 0, 0);
}
#define WVM(N) asm volatile("s_waitcnt vmcnt(%0)" ::"i"(N) : "memory")
#define SB() __builtin_amdgcn_sched_barrier(0)
// read-fence: all prior ds_reads complete before anything below issues.
// Closes the WAR window where the next STAGE's async LDS-write could land in
// the buffer the current iteration's ds_reads are still consuming (R11 bug).
#define FENCE_RW()                                       \
  do {                                                   \
    asm volatile("s_waitcnt lgkmcnt(0)" ::: "memory");   \
    __builtin_amdgcn_sched_barrier(0);                   \
  } while (0)

// Bank-conflict swizzle (rule #21 / T2): staging tiles are [R][8 blk] of 16 B;
// row stride 128 B = 32 banks, so an unswizzled column read is 16-way
// conflicted (R12: 8.97M conflict cycles). global_load_lds writes linearly ->
// permute the GLOBAL source block (blk ^ (row&7)) and read with the same XOR:
// each 16-lane group then spreads over 8 bank-quads (2-way = free, m136).

// ---- kernel 1: fp32 -> bf16 (x padded, W concat) + mask zero-padded fp32 ----
__global__ __launch_bounds__(256) void convert_kernel(
    const float* __restrict__ x, const float* __restrict__ Wq,
    const float* __restrict__ Wk, const float* __restrict__ Wv,
    const float* __restrict__ mask, unsigned short* __restrict__ xbf,
    unsigned short* __restrict__ wbf, float* __restrict__ mpad) {
  int i = blockIdx.x * 256 + threadIdx.x;
  const int N1 = B_ * SP * EIN_;   // 1,032,192
  const int N2 = NCOL3 * EIN_;     // 491,520
  const int N3 = SP * SPAD;        // 1,032,192
  if (i < N1) {
    int b = i / (SP * EIN_);
    int rem = i % (SP * EIN_);
    int row = rem / EIN_;
    int e = rem % EIN_;
    float v = (row < S_) ? x[((size_t)(b * S_ + row)) * EIN_ + e] : 0.0f;
    xbf[i] = f2bf(v);
  } else if (i < N1 + N2) {
    int j = i - N1;
    int col = j / EIN_;
    int e = j % EIN_;
    int mat = col / NCOL;
    int hcol = col % NCOL;
    const float* W = (mat == 0) ? Wq : (mat == 1) ? Wk : Wv;
    wbf[j] = f2bf(W[(size_t)hcol * EIN_ + e]);
  } else if (i < N1 + N2 + N3) {
    int j = i - N1 - N2;
    int row = j >> 10;
    int col = j & 1023;
    mpad[j] = (row < S_ && col < S_) ? mask[(size_t)row * S_ + col] : 0.0f;
  }
}

// ---------------- kernel 2: projection GEMM (MFMA bf16), 6-way N split ------
__global__ __launch_bounds__(256, 4) void proj_kernel(
    const unsigned short* __restrict__ xbf, const unsigned short* __restrict__ wbf,
    const float* __restrict__ bq, const float* __restrict__ bk,
    const float* __restrict__ bv, unsigned short* __restrict__ qbf,
    unsigned short* __restrict__ kbf, unsigned short* __restrict__ vrow) {
  int tid = threadIdx.x;
  int wv_ = tid >> 6;
  int l = tid & 63;
  int qd = l >> 4;
  int c = l & 15;
  int bid = blockIdx.x;
  int g = bid % 6;
  int t2 = bid / 6;
  int b = t2 / 63;
  int tile = t2 % 63;
  int s0 = tile * 16;

  bf16x8 af[8];
  const unsigned short* xrowp = xbf + (size_t)(b * SP + s0 + c) * EIN_;
#pragma unroll
  for (int ks = 0; ks < 8; ++ks)
    af[ks] = *(const bf16x8*)(xrowp + ks * 32 + qd * 8);

  for (int nt = g * 20 + wv_; nt < g * 20 + 20; nt += 4) {
    int col0 = nt * 16;
    f32x4 acc = {0.f, 0.f, 0.f, 0.f};
    const unsigned short* wrow = wbf + (size_t)(col0 + c) * EIN_;
    bf16x8 bf0[4], bf1[4];
#pragma unroll
    for (int j = 0; j < 4; ++j) bf0[j] = *(const bf16x8*)(wrow + j * 32 + qd * 8);
#pragma unroll
    for (int j = 0; j < 4; ++j) bf1[j] = *(const bf16x8*)(wrow + (4 + j) * 32 + qd * 8);
#pragma unroll
    for (int j = 0; j < 4; ++j)
      acc = __builtin_amdgcn_mfma_f32_16x16x32_bf16(af[j], bf0[j], acc, 0, 0, 0);
#pragma unroll
    for (int j = 0; j < 4; ++j)
      acc = __builtin_amdgcn_mfma_f32_16x16x32_bf16(af[4 + j], bf1[j], acc, 0, 0, 0);
    int col = col0 + c;
    int mat = col / NCOL;
    int hcol = col % NCOL;
    int hh = hcol >> 6;
    int o = hcol & 63;
    const float* bias = (mat == 0) ? bq : (mat == 1) ? bk : bv;
    float bb = bias[hcol];
    unsigned short* dst = (mat == 0) ? qbf : (mat == 1) ? kbf : vrow;
    size_t base = ((size_t)(b * H_ + hh)) * SPAD * EOUT_ + o;
#pragma unroll
    for (int i = 0; i < 4; ++i) {
      int srow = s0 + qd * 4 + i;
      float v = (srow < S_) ? (acc[i] + bb) : 0.0f;  // zero pad rows
      dst[base + (size_t)srow * EOUT_] = f2bf(v);
    }
  }
}

// ---------------- kernel 3: v [t][o] -> vT [o][t] ----------------
__global__ __launch_bounds__(256) void transpose_v(
    const unsigned short* __restrict__ vrow, unsigned short* __restrict__ vT) {
  __shared__ unsigned short tl[64 * 65];
  int bid = blockIdx.x;
  int bh = bid >> 4;
  int t0 = (bid & 15) * 64;
  int tid = threadIdx.x;
#pragma unroll
  for (int i = 0; i < 16; ++i) {
    int idx = i * 256 + tid;
    int o = idx & 63;
    int t_l = idx >> 6;
    int row = t0 + t_l;
    tl[o * 65 + t_l] =
        (row < SP) ? vrow[((size_t)bh * SPAD + row) * EOUT_ + o] : (unsigned short)0;
  }
  __syncthreads();
#pragma unroll
  for (int i = 0; i < 16; ++i) {
    int idx = i * 256 + tid;
    int t_l = idx & 63;
    int o = idx >> 6;
    vT[((size_t)bh * EOUT_ + o) * SPAD + t0 + t_l] = tl[o * 65 + t_l];
  }
}

// ---------------- kernel 4: attention with async-staged K and V -------------
// R12 structure + XOR bank-swizzle on the staging tiles. LDS: sc 32528 + rs 64
// + kst 16384 = 48976 B -> 3 blocks/CU.
__global__ __launch_bounds__(256) void attn_kernel(
    const unsigned short* __restrict__ qbf, const unsigned short* __restrict__ kbf,
    const unsigned short* __restrict__ vT, const float* __restrict__ mpad,
    float* __restrict__ rsbuf, float* __restrict__ out) {
  __shared__ __align__(16) unsigned short kst[2][4][16 * 64];  // 16 KB staging
  __shared__ unsigned short sc[16 * SCW + 8];  // +8 bf16 = 16 B zero guard
  __shared__ float rs[16];

  int tid = threadIdx.x;
  int wv_ = tid >> 6;
  int l = tid & 63;
  int qd = l >> 4;
  int c = l & 15;

  int bid0 = blockIdx.x;
  int x_ = bid0 & 7;        // XCD (hw round-robins consecutive bids)
  int s_ = bid0 >> 3;       // 0..319 slot within XCD
  int xr = x_ >> 2;         // tile half (0..1)
  int xc = x_ & 3;          // bh quarter (0..3)
  int sub = s_ / 160;       // 5-bh sub-phase (0..1)
  int m_ = s_ % 160;
  int ti = m_ / 5;          // 0..31
  int bhi = m_ % 5;
  int tile = xr * 32 + ti;  // 0..63
  if (tile >= 63) return;   // 40 pad blocks (uniform, before any barrier)
  int bh_ = xc * 10 + sub * 5 + bhi;  // 0..39
  int b = bh_ / 10;
  int h = bh_ % 10;
  int s0 = tile * 16;

  if (tid < 16) rs[tid] = 0.0f;

  float* concat = out;  // [B,S,640]

  size_t bh = (size_t)(b * H_ + h);
  const unsigned short* qb = qbf + bh * SPAD * EOUT_;
  const unsigned short* kb = kbf + bh * SPAD * EOUT_;
  const unsigned short* vb = vT + bh * EOUT_ * SPAD;

  bf16x8 aq0 = *(const bf16x8*)(qb + (size_t)(s0 + c) * EOUT_ + qd * 8);
  bf16x8 aq1 = *(const bf16x8*)(qb + (size_t)(s0 + c) * EOUT_ + 32 + qd * 8);

  // swizzled source block: lane covers row (l>>3), LDS blk (l&7), so fetch
  // global blk (l&7)^(l>>3). LDS slot (R,B) then holds global (R, B^(R&7)).
  int swzblk = ((l & 7) ^ (l >> 3)) * 8;

  // stage K tile idx (rows t0..t0+15, all 64 cols) into kst[idx&1][wv_]
#define STAGE_K(IDX)                                                          \
  do {                                                                        \
    int t0_ = (wv_ + 4 * (IDX)) * 16;                                         \
    const unsigned short* src_ = kb + (size_t)t0_ * EOUT_;                    \
    unsigned short* dst_ = &kst[(IDX) & 1][wv_][0];                           \
    stage16(src_ + (size_t)(l >> 3) * EOUT_ + swzblk, dst_);                  \
    stage16(src_ + (size_t)(8 + (l >> 3)) * EOUT_ + swzblk, dst_ + 512);      \
  } while (0)

  // ---- phase A: scores = (Q K^T)/16 via staged K pipeline ----
  STAGE_K(0);
  STAGE_K(1);
#pragma unroll
  for (int idx = 0; idx < 16; ++idx) {
    if (idx < 15) {
      WVM(2);  // tile idx landed (only tile idx+1's 2 ops may remain)
    } else {
      WVM(0);
    }
    SB();  // ds_reads below must not hoist above the wait
    if (wv_ < 3 || idx < 15) {  // wv_=3,idx=15 is the pad tile
      int t0 = (wv_ + 4 * idx) * 16;
      const unsigned short* kl = &kst[idx & 1][wv_][0];
      bf16x8 k0 = *(const bf16x8*)(kl + c * 64 + ((qd ^ (c & 7)) * 8));
      bf16x8 k1 = *(const bf16x8*)(kl + c * 64 + (((qd + 4) ^ (c & 7)) * 8));
      f32x4 acc = {0.f, 0.f, 0.f, 0.f};
      acc = __builtin_amdgcn_mfma_f32_16x16x32_bf16(aq0, k0, acc, 0, 0, 0);
      acc = __builtin_amdgcn_mfma_f32_16x16x32_bf16(aq1, k1, acc, 0, 0, 0);
#pragma unroll
      for (int i = 0; i < 4; ++i)
        sc[(qd * 4 + i) * SCW + t0 + c] = f2bf(acc[i] * 0.0625f);
    }
    FENCE_RW();  // ds_reads complete before next stage overwrites the buffer
    if (idx < 14) STAGE_K(idx + 2);
  }
  // cols 1008..1015 of each row + the 16 B guard after row 15 must be finite
  if (tid < 128) sc[(tid >> 3) * SCW + 1008 + (tid & 7)] = 0;
  if (tid < 8) sc[16 * SCW + tid] = 0;
  __syncthreads();

  // ---- phase B: row-per-wave; l = exp(s)*mask, rs per row; hoisted loads ----
#pragma unroll
  for (int rr = 0; rr < 4; ++rr) {
    int r = wv_ * 4 + rr;
    int srow = s0 + r;
    if (srow < S_) {
      const float* mrow = mpad + (size_t)srow * SPAD;
      bf16x4 sv[4];
      f32x4 mv[4];
      bool tail = (l < 60);
#pragma unroll
      for (int ci = 0; ci < 3; ++ci) {
        int t0c = ci * 256 + 4 * l;
        sv[ci] = *(const bf16x4*)&sc[r * SCW + t0c];
        mv[ci] = *(const f32x4*)(mrow + t0c);
      }
      if (tail) {
        int t0c = 768 + 4 * l;
        sv[3] = *(const bf16x4*)&sc[r * SCW + t0c];
        mv[3] = *(const f32x4*)(mrow + t0c);
      }
      float nacc = 0.0f;
#pragma unroll
      for (int ci = 0; ci < 3; ++ci) {
        int t0c = ci * 256 + 4 * l;
        bf16x4 lvv;
#pragma unroll
        for (int j = 0; j < 4; ++j) {
          float e = __expf(bf2f((unsigned short)sv[ci][j]));
          float lval = e * mv[ci][j];  // mpad pad cols are 0 -> lval 0
          nacc += lval * lval;
          lvv[j] = (short)f2bf(lval);
        }
        *(bf16x4*)&sc[r * SCW + t0c] = lvv;
      }
      if (tail) {  // tail chunk: cols 768..1007
        int t0c = 768 + 4 * l;
        bf16x4 lvv;
#pragma unroll
        for (int j = 0; j < 4; ++j) {
          float e = __expf(bf2f((unsigned short)sv[3][j]));
          float lval = e * mv[3][j];
          nacc += lval * lval;
          lvv[j] = (short)f2bf(lval);
        }
        *(bf16x4*)&sc[r * SCW + t0c] = lvv;
      }
      nacc += __shfl_xor(nacc, 1);
      nacc += __shfl_xor(nacc, 2);
      nacc += __shfl_xor(nacc, 4);
      nacc += __shfl_xor(nacc, 8);
      nacc += __shfl_xor(nacc, 16);
      nacc += __shfl_xor(nacc, 32);
      if (l == 0) rs[r] = 1.0f / fmaxf(sqrtf(nacc), 1e-12f);
    }
  }
  __syncthreads();

  if (tid < 16) rsbuf[((size_t)bh * 63 + tile) * 16 + tid] = rs[tid];

  // ---- phase D: out = (loc V) * rs[row] via staged V pipeline ----
  // V granule p = 64 cols (2 ksteps) of this wave's 16-row strip; reuses kst
  // (phase A's stage ops fully drained by the barrier's vmcnt(0)).
#define STAGE_V(P)                                                            \
  do {                                                                        \
    const unsigned short* src_ = vb + (size_t)(wv_ * 16) * SPAD + (P) * 64;   \
    unsigned short* dst_ = &kst[(P) & 1][wv_][0];                             \
    stage16(src_ + (size_t)(l >> 3) * SPAD + swzblk, dst_);                   \
    stage16(src_ + (size_t)(8 + (l >> 3)) * SPAD + swzblk, dst_ + 512);       \
  } while (0)

  f32x4 oacc = {0.f, 0.f, 0.f, 0.f};
  const unsigned short* scrow = &sc[c * SCW + qd * 8];
  STAGE_V(0);
  STAGE_V(1);
#pragma unroll
  for (int p = 0; p < 16; ++p) {
    if (p < 15) {
      WVM(2);
    } else {
      WVM(0);
    }
    SB();
    const unsigned short* kl = &kst[p & 1][wv_][0];
#pragma unroll
    for (int sp = 0; sp < 2; ++sp) {
      int kstep = p * 2 + sp;
      bf16x8 a = *(const bf16x8*)(scrow + (size_t)kstep * 32);
      bf16x8 v = *(const bf16x8*)(kl + c * 64 + (((sp * 4 + qd) ^ (c & 7)) * 8));
      oacc = __builtin_amdgcn_mfma_f32_16x16x32_bf16(a, v, oacc, 0, 0, 0);
    }
    FENCE_RW();  // kst/sc ds_reads complete before next stage issues
    if (p < 14) STAGE_V(p + 2);
  }
#pragma unroll
  for (int i = 0; i < 4; ++i) {
    int row = qd * 4 + i;
    int srow = s0 + row;
    if (srow < S_)
      concat[((size_t)(b * S_) + srow) * NCOL + h * EOUT_ + wv_ * 16 + c] =
          oacc[i] * rs[row];
  }
#undef STAGE_K
#undef STAGE_V
}

// ---- kernel 5: wsum via async LDS-staged K pipeline [R12 + swizzle] ----
__global__ __launch_bounds__(256) void wsum_kernel(
    const unsigned short* __restrict__ qbf, const unsigned short* __restrict__ kbf,
    const float* __restrict__ rsbuf, const float* __restrict__ mpad,
    float* __restrict__ out) {
  __shared__ unsigned short kst[2][4][32 * 64];  // 32 KB: [buf][wave][row*64+col]
  __shared__ float wrs[H_ * 16];
  int tid = threadIdx.x;
  int wv_ = tid >> 6;
  int l = tid & 63;
  int qd = l >> 4;
  int c = l & 15;
  int lrow = l >> 3;  // staging: lane covers row lrow (mod 8), 16B-block lblk
  int lblk = l & 7;
  int bid0 = blockIdx.x;
  // XCD swizzle: 1008 = 8 * 126; co-locate same-tile blocks per XCD.
  int bid = (bid0 & 7) * 126 + (bid0 >> 3);
  int tchunk = bid & 3;
  int rem = bid >> 2;
  int tile = rem % 63;
  int b = rem / 63;
  int s0 = tile * 16;
  int tb = tchunk * 256 + wv_ * 64;

  if (tid < H_ * 16) {
    int hh = tid >> 4, row = tid & 15;
    wrs[tid] = rsbuf[((size_t)(b * H_ + hh) * 63 + tile) * 16 + row];
  }
  __syncthreads();  // before any staging: barrier's vmcnt drain is harmless here

  const unsigned short* kbase = kbf + (size_t)(b * H_) * SPAD * EOUT_;
  const unsigned short* qbase = qbf + (size_t)(b * H_) * SPAD * EOUT_;
  const size_t qoff = (size_t)(s0 + c) * EOUT_ + qd * 8;
  int swz = (lblk ^ lrow) * 8;  // LDS row = i*8+lrow -> row&7 = lrow

  // stage half-head M (head M>>1, rows [(M&1)*32, +32) of this wave's strip)
#define STAGE_HALF(M)                                                         \
  do {                                                                        \
    int h_ = (M) >> 1, p_ = (M) & 1;                                          \
    const unsigned short* kb_ = kbase + (size_t)h_ * SPAD * EOUT_;            \
    unsigned short* dst_ = &kst[(M) & 1][wv_][0];                             \
    _Pragma("unroll") for (int i_ = 0; i_ < 4; ++i_) {                        \
      int r_ = p_ * 32 + i_ * 8 + lrow;                                       \
      stage16(kb_ + (size_t)(tb + r_) * EOUT_ + swz, dst_ + i_ * 512);        \
    }                                                                         \
  } while (0)

  float wacc[16];
#pragma unroll
  for (int i = 0; i < 16; ++i) wacc[i] = 0.0f;

  STAGE_HALF(0);
  STAGE_HALF(1);

  bf16x8 q0, q1;
  for (int m = 0; m < 20; ++m) {
    int h = m >> 1;
    int p = m & 1;
    if (p == 0) {  // Q fragments for this head (compiler-managed latency)
      const unsigned short* qb = qbase + (size_t)h * SPAD * EOUT_;
      q0 = *(const bf16x8*)(qb + qoff);
      q1 = *(const bf16x8*)(qb + qoff + 32);
    }
    if (m < 19) {
      WVM(4);  // half m done (>=4 younger stage ops follow it in the queue)
    } else {
      WVM(0);
    }
    SB();  // nothing (esp. the ds_reads below) may hoist above the wait
    const unsigned short* kl = &kst[m & 1][wv_][0];
#pragma unroll
    for (int sp = 0; sp < 2; ++sp) {
      int st = p * 2 + sp;
      int rh = sp * 16 + c;  // row within the 32-row half
      const unsigned short* kr = kl + rh * 64;
      bf16x8 k0 = *(const bf16x8*)(kr + ((qd ^ (rh & 7)) * 8));
      bf16x8 k1 = *(const bf16x8*)(kr + (((qd + 4) ^ (rh & 7)) * 8));
      f32x4 a = {0.f, 0.f, 0.f, 0.f};
      a = __builtin_amdgcn_mfma_f32_16x16x32_bf16(q0, k0, a, 0, 0, 0);
      a = __builtin_amdgcn_mfma_f32_16x16x32_bf16(q1, k1, a, 0, 0, 0);
#pragma unroll
      for (int i = 0; i < 4; ++i)
        wacc[st * 4 + i] += wrs[h * 16 + qd * 4 + i] * exp2f(a[i] * C1EXP);
    }
    FENCE_RW();  // kst ds_reads complete before next stage issues (WAR fix)
    if (m < 18) STAGE_HALF(m + 2);
  }

  float* wsum = out + (size_t)B_ * S_ * NCOL;
#pragma unroll
  for (int st = 0; st < 4; ++st) {
    int t = tb + st * 16 + c;
#pragma unroll
    for (int i = 0; i < 4; ++i) {
      int srow = s0 + qd * 4 + i;
      if (srow < S_ && t < S_)
        wsum[((size_t)b * S_ + srow) * S_ + t] =
            wacc[st * 4 + i] * mpad[(size_t)srow * SPAD + t];
    }
  }
#undef STAGE_HALF
}

extern "C" void kernel_launch(void* const* d_in, const int* in_sizes, int n_in,
                              void* d_out, int out_size, void* d_ws, size_t ws_size,
                              hipStream_t stream) {
  const float* x = (const float*)d_in[0];
  const float* mask = (const float*)d_in[1];
  const float* Wq = (const float*)d_in[2];
  const float* bq = (const float*)d_in[3];
  const float* Wk = (const float*)d_in[4];
  const float* bk = (const float*)d_in[5];
  const float* Wv = (const float*)d_in[6];
  const float* bv = (const float*)d_in[7];
  float* out = (float*)d_out;

  char* ws = (char*)d_ws;
  const size_t NEED = 28308992;
  if (ws_size < NEED) return;  // fail cleanly rather than OOB
  unsigned short* xbf  = (unsigned short*)ws;              // 2,064,384 B
  unsigned short* wbf  = (unsigned short*)(ws + 2064384);  //   983,040 B
  unsigned short* qbf  = (unsigned short*)(ws + 3047424);  // 5,242,880 B
  unsigned short* kbf  = (unsigned short*)(ws + 8290304);  // 5,242,880 B
  unsigned short* vrow = (unsigned short*)(ws + 13533184); // 5,242,880 B
  unsigned short* vT   = (unsigned short*)(ws + 18776064); // 5,242,880 B
  float*          mpad = (float*)(ws + 24018944);          // 4,128,768 B
  float*          rsbuf = (float*)(ws + 28147712);         //   161,280 B

  convert_kernel<<<9984, 256, 0, stream>>>(x, Wq, Wk, Wv, mask, xbf, wbf, mpad);
  proj_kernel<<<1512, 256, 0, stream>>>(xbf, wbf, bq, bk, bv, qbf, kbf, vrow);
  transpose_v<<<640, 256, 0, stream>>>(vrow, vT);
  attn_kernel<<<2560, 256, 0, stream>>>(qbf, kbf, vT, mpad, rsbuf, out);
  wsum_kernel<<<1008, 256, 0, stream>>>(qbf, kbf, rsbuf, mpad, out);
}